// Round 13
// baseline (1758.957 us; speedup 1.0000x reference)
//
#include <hip/hip_runtime.h>
#include <math.h>

typedef unsigned short u16;
typedef unsigned int   u32;
typedef __bf16  bf16x8 __attribute__((ext_vector_type(8)));
typedef float   f32x4  __attribute__((ext_vector_type(4)));
typedef u16     u16x8  __attribute__((ext_vector_type(8)));
typedef u16     u16x4  __attribute__((ext_vector_type(4)));

__device__ __forceinline__ u16 f2bf(float f) {
  u32 u = __builtin_bit_cast(u32, f);
  u32 r = (u + 0x7fffu + ((u >> 16) & 1u)) >> 16;
  return (u16)r;
}
__device__ __forceinline__ float bf2f(u16 h) {
  u32 u = ((u32)h) << 16;
  return __builtin_bit_cast(float, u);
}
__device__ __forceinline__ void gload16(const void* g, void* l) {
  __builtin_amdgcn_global_load_lds((const __attribute__((address_space(1))) void*)g,
                                   (__attribute__((address_space(3))) void*)l, 16, 0, 0);
}
__device__ __forceinline__ bf16x8 ld_bf8(const u16* p) {
  u16x8 v = *(const u16x8*)p;
  return __builtin_bit_cast(bf16x8, v);
}
__device__ __forceinline__ f32x4 mfma16(bf16x8 a, bf16x8 b, f32x4 c) {
  return __builtin_amdgcn_mfma_f32_16x16x32_bf16(a, b, c, 0, 0, 0);
}

// ---------------------------------------------------------------- weights
struct ConvP {
  const float *wq, *wk, *wv, *wo, *wi, *wf;   // layer-0 bases
  u16 *oqkv, *oo, *oi, *of;                   // dst bases
  long doqkv, doo, doi, dof;                  // dst layer strides (elements; 0 = rotating)
};
// transpose+convert f32 [K,N] -> bf16 [N,K]; 64x64 tiles, 1728 tiles/layer.
__global__ __launch_bounds__(256) void conv_weights(ConvP p, int l0) {
  int l = l0 + blockIdx.x / 1728;
  int t = blockIdx.x % 1728;
  const float* in; u16* out; int K, N, tn, tk;
  if (t < 432) { int wh = t / 144, tt = t % 144;
    in = (wh==0 ? p.wq : (wh==1 ? p.wk : p.wv)) + (size_t)l*768*768;
    out = p.oqkv + (size_t)l*p.doqkv + (size_t)wh * 768 * 768;
    K = 768; N = 768; tn = tt % 12; tk = tt / 12;
  } else if (t < 576) { int tt = t - 432;
    in = p.wo + (size_t)l*768*768; out = p.oo + (size_t)l*p.doo;
    K=768;  N=768;  tn=tt%12; tk=tt/12;
  } else if (t < 1152) { int tt = t - 576;
    in = p.wi + (size_t)l*768*3072; out = p.oi + (size_t)l*p.doi;
    K=768;  N=3072; tn=tt%48; tk=tt/48;
  } else { int tt = t - 1152;
    in = p.wf + (size_t)l*768*3072; out = p.of + (size_t)l*p.dof;
    K=3072; N=768;  tn=tt%12; tk=tt/12;
  }
  int n0 = tn*64, k0 = tk*64;
  __shared__ float tile[64][65];
  int tid = threadIdx.x;
  int tx = tid & 15, ry = tid >> 4;     // 16 float4-cols, 16 rows/pass
  #pragma unroll
  for (int j = 0; j < 4; ++j) {
    int kk = j*16 + ry;
    float4 rv = *(const float4*)(in + (size_t)(k0 + kk) * N + n0 + tx*4);
    tile[kk][tx*4+0] = rv.x; tile[kk][tx*4+1] = rv.y;
    tile[kk][tx*4+2] = rv.z; tile[kk][tx*4+3] = rv.w;
  }
  __syncthreads();
  #pragma unroll
  for (int j = 0; j < 4; ++j) {
    int nn = j*16 + ry;
    u16x4 ov;
    ov[0] = f2bf(tile[tx*4+0][nn]); ov[1] = f2bf(tile[tx*4+1][nn]);
    ov[2] = f2bf(tile[tx*4+2][nn]); ov[3] = f2bf(tile[tx*4+3][nn]);
    *(u16x4*)(out + (size_t)(n0 + nn) * K + k0 + tx*4) = ov;
  }
}

// ---------------------------------------------------------------- GEMM (A[M,K] bf16 x B^T[N,K] bf16)
struct GP {
  const u16* A; const u16* B;
  int K, N;
  long sA, sB, sOut;
  const float* bias; const float* res;
  float* outF; u16* outB;
  const float* bq; const float* bk; const float* bv;
  u16* qO; u16* kO; u16* vO;
};

// EPI: 0=QKV scatter, 2=f32 partial, 3=gelu->bf16
template<int BM, int BN, int WAVES, int EPI, int KS>
__global__ __launch_bounds__(WAVES*64) void gemm_bt(GP p) {
  constexpr int THREADS = WAVES * 64;
  constexpr int WC = WAVES / 2;
  constexpr int WM = BM / 2, WN = BN / WC, MR = WM / 16, NR = WN / 16;
  constexpr int AIT = BM * 64 / (THREADS * 8);
  constexpr int BIT = BN * 64 / (THREADS * 8);
  const int tid = threadIdx.x;
  const int wave = tid >> 6, lane = tid & 63;
  const int wr = wave / WC, wc = wave % WC;
  const int wm0 = wr * WM, wn0 = wc * WN;
  const int bn = blockIdx.x, bm = blockIdx.y, bz = blockIdx.z;
  const int K = p.K;
  const int kLen = K / KS;
  const int kBeg = (KS > 1) ? bz * kLen : 0;
  const u16* A  = p.A + ((KS > 1) ? 0 : (size_t)bz * p.sA);
  const u16* Bp = p.B + ((KS > 1) ? 0 : (size_t)bz * p.sB);
  const int rowA0 = bm * BM, colB0 = bn * BN;

  __shared__ __align__(16) u16 lds[(BM + BN) * 64];
  u16* Al = lds; u16* Bl = lds + BM * 64;

  f32x4 acc[MR][NR];
  #pragma unroll
  for (int i = 0; i < MR; ++i)
    #pragma unroll
    for (int j = 0; j < NR; ++j) acc[i][j] = f32x4{0.f,0.f,0.f,0.f};

  for (int kt = kBeg; kt < kBeg + kLen; kt += 64) {
    #pragma unroll
    for (int it = 0; it < AIT; ++it) {
      int e = tid * 8 + it * THREADS * 8;
      gload16(A + (size_t)(rowA0 + (e >> 6)) * K + kt + (e & 63), Al + e);
    }
    #pragma unroll
    for (int it = 0; it < BIT; ++it) {
      int e = tid * 8 + it * THREADS * 8;
      gload16(Bp + (size_t)(colB0 + (e >> 6)) * K + kt + (e & 63), Bl + e);
    }
    __syncthreads();
    #pragma unroll
    for (int ks = 0; ks < 2; ++ks) {
      bf16x8 av[MR]; bf16x8 bw[NR];
      #pragma unroll
      for (int mf = 0; mf < MR; ++mf)
        av[mf] = ld_bf8(Al + (wm0 + mf*16 + (lane&15))*64 + ks*32 + (lane>>4)*8);
      #pragma unroll
      for (int nf = 0; nf < NR; ++nf)
        bw[nf] = ld_bf8(Bl + (wn0 + nf*16 + (lane&15))*64 + ks*32 + (lane>>4)*8);
      #pragma unroll
      for (int mf = 0; mf < MR; ++mf)
        #pragma unroll
        for (int nf = 0; nf < NR; ++nf)
          acc[mf][nf] = mfma16(av[mf], bw[nf], acc[mf][nf]);
    }
    __syncthreads();
  }

  #pragma unroll
  for (int mf = 0; mf < MR; ++mf) {
    #pragma unroll
    for (int nf = 0; nf < NR; ++nf) {
      int col = colB0 + wn0 + nf*16 + (lane & 15);
      #pragma unroll
      for (int reg = 0; reg < 4; ++reg) {
        int row = rowA0 + wm0 + mf*16 + (lane >> 4)*4 + reg;
        float v = acc[mf][nf][reg];
        if constexpr (EPI == 0) { // QKV scatter
          int wh = col / 768, cc = col % 768;
          int hh = cc >> 6, d = col & 63;
          int b = row >> 9, s = row & 511;
          const float* bias = wh==0 ? p.bq : (wh==1 ? p.bk : p.bv);
          u16 o = f2bf(v + bias[cc]);
          if (wh == 0)      p.qO[((((size_t)b*12 + hh)*512 + s) << 6) + d] = o;
          else if (wh == 1) p.kO[((((size_t)b*12 + hh)*512 + s) << 6) + d] = o;
          else              p.vO[((((size_t)b*12 + hh)*64  + d) << 9) + s] = o;
        } else if constexpr (EPI == 2) { // raw f32 partial
          p.outF[(size_t)bz * p.sOut + (size_t)row * p.N + col] = v;
        } else { // gelu -> bf16
          float xg = v + p.bias[col];
          float gg = 0.5f * xg * (1.f + erff(xg * 0.70710678118f));
          p.outB[(size_t)row * p.N + col] = f2bf(gg);
        }
      }
    }
  }
}

// ---------------------------------------------------------------- flash attention v5: no LDS staging, no loop barriers
// block: (head, 32 q-rows), 4 waves (wr=row-half, wc=t-half). K/V MFMA fragments
// read DIRECT from global (L2-resident; 16 blocks/head on one XCD). LDS only for
// mask bias, wave-private P bounce, and the final two-partial merge.
template<int RAT>
__global__ __launch_bounds__(256) void flash_attn(
    const u16* __restrict__ q, const u16* __restrict__ k, const u16* __restrict__ v,
    const int* __restrict__ mask, u16* __restrict__ ctx,
    const float* __restrict__ kr, const int* __restrict__ rel,
    float* __restrict__ wbins) {
  const int head = blockIdx.x;   // 0..47 (48 % 8 == 0 -> same head on one XCD)
  const int bm = blockIdx.y;     // 0..15
  const int b = head / 12, hh = head % 12;
  const int tid = threadIdx.x, wave = tid >> 6, lane = tid & 63;
  const int wr = wave >> 1, wc = wave & 1;
  const int row0 = bm * 32;
  const u16* qb = q + (size_t)head * 512 * 64;
  const u16* kb = k + (size_t)head * 512 * 64;
  const u16* vb = v + (size_t)head * 64 * 512;   // [d][t]

  __shared__ __align__(16) u16 pw[4][16*72];     // P bounce; aliased: kr bf16 (RAT init), f32 merge buf
  __shared__ float em_lds[512];
  __shared__ float mlb[2][16][2];
  __shared__ float qlds[RAT ? 32 : 1][RAT ? 52 : 1];
  __shared__ float wlds[RAT ? 2 : 1][RAT ? 32 : 1][RAT ? 50 : 1];
  __shared__ float scl[RAT ? 2 : 1][RAT ? 32 : 1];
  __shared__ float aex[RAT ? 32 : 1][RAT ? 3 : 1];

  for (int i = tid; i < 512; i += 256)
    em_lds[i] = -10000.f * (1.f - (float)mask[b*512 + i]);
  u16* Krl = (u16*)pw;                          // 64x64 bf16 = 8KB <= pw 9KB
  if constexpr (RAT) {
    for (int i = tid; i < 2*32*50; i += 256) ((float*)wlds)[i] = 0.f;
    for (int i = tid; i < 64*64; i += 256) {
      int r = i >> 6, c = i & 63;
      Krl[i] = (r < 50) ? f2bf(kr[r*64 + c]) : (u16)0;
    }
  }

  // Q fragments direct from global (L2-resident)
  const int qrow = row0 + wr*16 + (lane & 15);
  const int g = lane >> 4;
  bf16x8 qf[2];
  qf[0] = ld_bf8(qb + (size_t)qrow*64 +      g*8);
  qf[1] = ld_bf8(qb + (size_t)qrow*64 + 32 + g*8);
  __syncthreads();   // em_lds (+Krl, wlds) ready

  if constexpr (RAT) {
    // qr[rl][rr] = q-row . kr-row, via 4 MFMAs per wave (wc owns rr-half)
    #pragma unroll
    for (int nf = 0; nf < 2; ++nf) {
      f32x4 a = f32x4{0.f,0.f,0.f,0.f};
      #pragma unroll
      for (int ks = 0; ks < 2; ++ks) {
        bf16x8 krf = ld_bf8(Krl + (wc*32 + nf*16 + (lane&15))*64 + ks*32 + g*8);
        a = mfma16(qf[ks], krf, a);
      }
      int rr = wc*32 + nf*16 + (lane & 15);
      if (rr < 50) {
        #pragma unroll
        for (int reg = 0; reg < 4; ++reg)
          qlds[wr*16 + g*4 + reg][rr] = a[reg];
      }
    }
    __syncthreads();   // qlds ready; pw (Krl) free for P tiles
  }

  f32x4 ctxacc[4];
  #pragma unroll
  for (int nf = 0; nf < 4; ++nf) ctxacc[nf] = f32x4{0.f,0.f,0.f,0.f};
  float mrun[4], lrun[4];
  #pragma unroll
  for (int r = 0; r < 4; ++r) { mrun[r] = -3.0e38f; lrun[r] = 0.f; }

  for (int it = 0; it < 4; ++it) {
    const int tbase = wc*256 + it*64;

    // S = Q K^T, K fragments direct from global/L2
    f32x4 s[4];
    #pragma unroll
    for (int nf = 0; nf < 4; ++nf) s[nf] = f32x4{0.f,0.f,0.f,0.f};
    #pragma unroll
    for (int ks = 0; ks < 2; ++ks)
      #pragma unroll
      for (int nf = 0; nf < 4; ++nf) {
        bf16x8 kf = ld_bf8(kb + (size_t)(tbase + nf*16 + (lane & 15))*64 + ks*32 + g*8);
        s[nf] = mfma16(qf[ks], kf, s[nf]);
      }

    u32 rr4[RAT ? 4 : 1];
    if constexpr (RAT) {
      #pragma unroll
      for (int nf = 0; nf < 4; ++nf) {
        int tt = tbase + nf*16 + (lane & 15);
        u32 pack = 0;
        #pragma unroll
        for (int reg = 0; reg < 4; ++reg) {
          int rl = wr*16 + g*4 + reg;
          int rr = rel[((size_t)(b*512 + row0 + rl))*512 + tt];
          pack |= (u32)rr << (8*reg);
          s[nf][reg] += qlds[rl][rr];
        }
        rr4[nf] = pack;
      }
    }

    float em4[4];
    #pragma unroll
    for (int nf = 0; nf < 4; ++nf) em4[nf] = em_lds[tbase + nf*16 + (lane & 15)];

    float scale_[4];
    #pragma unroll
    for (int reg = 0; reg < 4; ++reg) {
      float pm = -3.0e38f;
      #pragma unroll
      for (int nf = 0; nf < 4; ++nf) {
        s[nf][reg] = s[nf][reg]*0.125f + em4[nf];
        pm = fmaxf(pm, s[nf][reg]);
      }
      #pragma unroll
      for (int o = 1; o < 16; o <<= 1) pm = fmaxf(pm, __shfl_xor(pm, o));
      float mnew = fmaxf(mrun[reg], pm);
      float sc = __expf(mrun[reg] - mnew);
      mrun[reg] = mnew;
      scale_[reg] = sc;
      float lsum = 0.f;
      #pragma unroll
      for (int nf = 0; nf < 4; ++nf) {
        float e = __expf(s[nf][reg] - mnew);
        s[nf][reg] = e;
        lsum += e;
      }
      #pragma unroll
      for (int o = 1; o < 16; o <<= 1) lsum += __shfl_xor(lsum, o);
      lrun[reg] = lrun[reg]*sc + lsum;
      if constexpr (RAT) {
        if ((lane & 15) == 0) scl[wc][wr*16 + g*4 + reg] = sc;
      }
    }

    if constexpr (RAT) {
      // bins are wave-exclusive rows of wlds[wc] -> no cross-wave race, no barrier
      for (int i = lane; i < 16*50; i += 64) {
        int r = i / 50;
        wlds[wc][wr*16 + r][i % 50] *= scl[wc][wr*16 + r];
      }
      #pragma unroll
      for (int nf = 0; nf < 4; ++nf)
        #pragma unroll
        for (int reg = 0; reg < 4; ++reg) {
          int rl = wr*16 + g*4 + reg;
          int rr = (rr4[nf] >> (8*reg)) & 255;
          atomicAdd(&wlds[wc][rl][rr], s[nf][reg]);
        }
    }

    // P -> wave-private LDS (in-order DS per wave; no barrier)
    #pragma unroll
    for (int nf = 0; nf < 4; ++nf)
      #pragma unroll
      for (int reg = 0; reg < 4; ++reg) {
        int qq = g*4 + reg;
        pw[wave][qq*72 + nf*16 + (lane & 15)] = f2bf(s[nf][reg]);
      }

    // rescale ctx, then PV; V fragments direct from global/L2
    #pragma unroll
    for (int nf = 0; nf < 4; ++nf)
      #pragma unroll
      for (int reg = 0; reg < 4; ++reg)
        ctxacc[nf][reg] *= scale_[reg];
    #pragma unroll
    for (int ks = 0; ks < 2; ++ks) {
      bf16x8 pf = ld_bf8(pw[wave] + (lane & 15)*72 + ks*32 + g*8);
      #pragma unroll
      for (int nf = 0; nf < 4; ++nf) {
        bf16x8 vf = ld_bf8(vb + (size_t)(nf*16 + (lane & 15))*512 + tbase + ks*32 + g*8);
        ctxacc[nf] = mfma16(pf, vf, ctxacc[nf]);
      }
    }
  }

  // ---- merge the two t-half partials (pw reused as f32 [32][66])
  __syncthreads();   // all waves done with pw P-tiles
  float* mergeF = (float*)pw;
  if (wc == 1) {
    #pragma unroll
    for (int nf = 0; nf < 4; ++nf)
      #pragma unroll
      for (int reg = 0; reg < 4; ++reg)
        mergeF[(wr*16 + g*4 + reg)*66 + nf*16 + (lane & 15)] = ctxacc[nf][reg];
    if ((lane & 15) == 0) {
      #pragma unroll
      for (int reg = 0; reg < 4; ++reg) {
        mlb[wr][g*4 + reg][0] = mrun[reg];
        mlb[wr][g*4 + reg][1] = lrun[reg];
      }
    }
  }
  __syncthreads();
  if (wc == 0) {
    float a1[4], a2[4], linv[4];
    #pragma unroll
    for (int reg = 0; reg < 4; ++reg) {
      int r = g*4 + reg;
      float m2 = mlb[wr][r][0], l2 = mlb[wr][r][1];
      float mn = fmaxf(mrun[reg], m2);
      a1[reg] = __expf(mrun[reg] - mn);
      a2[reg] = __expf(m2 - mn);
      linv[reg] = 1.f / (lrun[reg]*a1[reg] + l2*a2[reg]);
      if constexpr (RAT) {
        if ((lane & 15) == 0) {
          aex[wr*16 + r][0] = a1[reg];
          aex[wr*16 + r][1] = a2[reg];
          aex[wr*16 + r][2] = linv[reg];
        }
      }
    }
    #pragma unroll
    for (int nf = 0; nf < 4; ++nf)
      #pragma unroll
      for (int reg = 0; reg < 4; ++reg) {
        int r = wr*16 + g*4 + reg;
        int qg = row0 + r;
        int d = nf*16 + (lane & 15);
        float v2 = mergeF[r*66 + d];
        ctx[((size_t)(b*512 + qg))*768 + hh*64 + d] =
            f2bf((ctxacc[nf][reg]*a1[reg] + v2*a2[reg]) * linv[reg]);
      }
  }
  if constexpr (RAT) {
    __syncthreads();
    for (int i = tid; i < 32*50; i += 256) {
      int sr = i / 50, rr = i % 50;
      wbins[((size_t)head*512 + row0 + sr)*50 + rr] =
          (wlds[0][sr][rr]*aex[sr][0] + wlds[1][sr][rr]*aex[sr][1]) * aex[sr][2];
    }
  }
}

// ---------------------------------------------------------------- RAT apply (layer 6)
__global__ __launch_bounds__(256) void rat_apply(const float* __restrict__ wbins,
    const float* __restrict__ vr, u16* __restrict__ ctx) {
  __shared__ float vrl[50*64];
  __shared__ float wl[32*50];
  int tid = threadIdx.x;
  int rows0 = blockIdx.x * 32;
  for (int i = tid; i < 50*64; i += 256) vrl[i] = vr[i];
  for (int i = tid; i < 32*50; i += 256) wl[i] = wbins[(size_t)rows0*50 + i];
  __syncthreads();
  int wave = tid >> 6, lane = tid & 63;
  #pragma unroll
  for (int i = 0; i < 8; ++i) {
    int r = wave*8 + i;
    size_t idx = (size_t)rows0 + r;
    float acc = 0.f;
    #pragma unroll
    for (int j = 0; j < 50; ++j) acc += wl[r*50 + j] * vrl[j*64 + lane];
    int s = (int)(idx & 511); size_t bh = idx >> 9;
    int b = (int)(bh / 12), hh = (int)(bh % 12);
    u16* cp = ctx + ((size_t)(b*512 + s))*768 + hh*64 + lane;
    *cp = f2bf(bf2f(*cp) + acc);
  }
}

// ---------------------------------------------------------------- embeddings + LN
__global__ __launch_bounds__(256) void embed_ln(const int* __restrict__ ids,
    const float* __restrict__ we, const float* __restrict__ pe, const float* __restrict__ te,
    const float* __restrict__ g, const float* __restrict__ b,
    float* __restrict__ hF, u16* __restrict__ hB) {
  int row = blockIdx.x, tid = threadIdx.x;
  int s = row & 511;
  int id = ids[row];
  float x[3];
  #pragma unroll
  for (int j = 0; j < 3; ++j) {
    int d = tid + j*256;
    x[j] = we[(size_t)id*768 + d] + pe[(size_t)s*768 + d] + te[d];
  }
  __shared__ float red[4];
  float sm = x[0] + x[1] + x[2];
  #pragma unroll
  for (int o = 32; o; o >>= 1) sm += __shfl_xor(sm, o);
  if (!(tid & 63)) red[tid >> 6] = sm;
  __syncthreads();
  float mean = (red[0]+red[1]+red[2]+red[3]) * (1.f/768.f);
  __syncthreads();
  float q = 0.f;
  #pragma unroll
  for (int j = 0; j < 3; ++j) { float d = x[j] - mean; q += d*d; }
  #pragma unroll
  for (int o = 32; o; o >>= 1) q += __shfl_xor(q, o);
  if (!(tid & 63)) red[tid >> 6] = q;
  __syncthreads();
  float inv = rsqrtf((red[0]+red[1]+red[2]+red[3]) * (1.f/768.f) + 1e-12f);
  #pragma unroll
  for (int j = 0; j < 3; ++j) {
    int d = tid + j*256;
    float y = (x[j] - mean) * inv * g[d] + b[d];
    hF[(size_t)row*768 + d] = y;
    hB[(size_t)row*768 + d] = f2bf(y);
  }
}

// LN over (p0[+p1][+p2][+p3]) + bias + res
__global__ __launch_bounds__(256) void ln_fused(const float* __restrict__ p0,
    const float* __restrict__ p1, const float* __restrict__ p2, const float* __restrict__ p3,
    int np, const float* __restrict__ bias, const float* __restrict__ res,
    const float* __restrict__ g, const float* __restrict__ b,
    float* __restrict__ oF, u16* __restrict__ oB) {
  int row = blockIdx.x, tid = threadIdx.x;
  size_t base = (size_t)row * 768;
  float v[3];
  #pragma unroll
  for (int j = 0; j < 3; ++j) {
    int d = tid + j*256;
    float x = p0[base + d];
    if (np > 1) x += p1[base + d];
    if (np > 2) x += p2[base + d];
    if (np > 3) x += p3[base + d];
    v[j] = x + bias[d] + res[base + d];
  }
  __shared__ float red[4];
  float sm = v[0] + v[1] + v[2];
  #pragma unroll
  for (int o = 32; o; o >>= 1) sm += __shfl_xor(sm, o);
  if (!(tid & 63)) red[tid >> 6] = sm;
  __syncthreads();
  float mean = (red[0]+red[1]+red[2]+red[3]) * (1.f/768.f);
  __syncthreads();
  float q = 0.f;
  #pragma unroll
  for (int j = 0; j < 3; ++j) { float d = v[j] - mean; q += d*d; }
  #pragma unroll
  for (int o = 32; o; o >>= 1) q += __shfl_xor(q, o);
  if (!(tid & 63)) red[tid >> 6] = q;
  __syncthreads();
  float inv = rsqrtf((red[0]+red[1]+red[2]+red[3]) * (1.f/768.f) + 1e-12f);
  #pragma unroll
  for (int j = 0; j < 3; ++j) {
    int d = tid + j*256;
    float y = (v[j] - mean) * inv * g[d] + b[d];
    oF[base + d] = y;
    oB[base + d] = f2bf(y);
  }
}

// ---------------------------------------------------------------- tail
__global__ __launch_bounds__(256) void pooler_k(const float* __restrict__ h,
    const float* __restrict__ w, const float* __restrict__ bias, float* __restrict__ out) {
  int b = blockIdx.x, tid = threadIdx.x;
  __shared__ float hr[768];
  for (int i = tid; i < 768; i += 256) hr[i] = h[((size_t)b*512)*768 + i];
  __syncthreads();
  float a0 = 0.f, a1 = 0.f, a2 = 0.f;
  for (int kk = 0; kk < 768; ++kk) {
    float hv = hr[kk];
    const float* wr = w + (size_t)kk*768;
    a0 += hv * wr[tid]; a1 += hv * wr[tid+256]; a2 += hv * wr[tid+512];
  }
  out[(size_t)b*768 + tid]       = tanhf(a0 + bias[tid]);
  out[(size_t)b*768 + tid + 256] = tanhf(a1 + bias[tid+256]);
  out[(size_t)b*768 + tid + 512] = tanhf(a2 + bias[tid+512]);
}

__global__ __launch_bounds__(256) void copy_out(const float* __restrict__ in, float* __restrict__ out) {
  size_t i = ((size_t)blockIdx.x * 256 + threadIdx.x) * 4;
  *(float4*)(out + i) = *(const float4*)(in + i);
}

// ---------------------------------------------------------------- host
extern "C" void kernel_launch(void* const* d_in, const int* in_sizes, int n_in,
                              void* d_out, int out_size, void* d_ws, size_t ws_size,
                              hipStream_t stream) {
  const int*   ids   = (const int*)d_in[0];
  const int*   rel   = (const int*)d_in[1];
  const int*   amask = (const int*)d_in[2];
  const float* we    = (const float*)d_in[3];
  const float* pe    = (const float*)d_in[4];
  const float* te    = (const float*)d_in[5];
  const float* eg    = (const float*)d_in[6];
  const float* ebb   = (const float*)d_in[7];
  const float* Wq    = (const float*)d_in[8];
  const float* bq    = (const float*)d_in[9];
  const float* Wk    = (const float*)d_in[10];
  const float* bk    = (const float*)d_in[11];
  const float* Wv    = (const float*)d_in[12];
  const float* bv    = (const float*)d_in[13];
  const float* Wo    = (const float*)d_in[14];
  const float* bo    = (const float*)d_in[15];
  const float* g1    = (const float*)d_in[16];
  const float* b1    = (const float*)d_in[17];
  const float* Wi    = (const float*)d_in[18];
  const float* bi    = (const float*)d_in[19];
  const float* Wf    = (const float*)d_in[20];
  const float* bfp   = (const float*)d_in[21];
  const float* g2    = (const float*)d_in[22];
  const float* b2    = (const float*)d_in[23];
  const float* krel  = (const float*)d_in[24];
  const float* vrel  = (const float*)d_in[25];
  const float* pwp   = (const float*)d_in[26];
  const float* pbp   = (const float*)d_in[27];
  (void)in_sizes; (void)n_in; (void)out_size;

  char* ws = (char*)d_ws;
  size_t off = 0;
  auto take = [&](size_t bytes) { char* p = ws + off; off += (bytes + 255) & ~(size_t)255; return p; };
  float* hF   = (float*)take((size_t)2048*768*4);
  u16*   hB   = (u16*)take((size_t)2048*768*2);
  float* atF  = (float*)take((size_t)2048*768*4);
  u16*   atB  = (u16*)take((size_t)2048*768*2);
  u16*   qB   = (u16*)take((size_t)2048*768*2);
  u16*   kB   = (u16*)take((size_t)2048*768*2);
  u16*   vB   = (u16*)take((size_t)2048*768*2);
  u16*   ctxB = (u16*)take((size_t)2048*768*2);
  float* tmpF = (float*)take((size_t)4*2048*768*4);   // 4 split-K partials
  u16*   ffB  = (u16*)take((size_t)2048*3072*2);
  float* wbF  = (float*)take((size_t)24576*50*4);
  const size_t PSTRIDE = (size_t)2048*768;

  // weight buffers: pre-convert all 12 layers in one launch if workspace allows
  const size_t WQKV = (size_t)2304*768, WWO = (size_t)768*768;
  const size_t WWI = (size_t)768*3072, WWF = (size_t)3072*768;
  const size_t wLayerBytes = (WQKV + WWO + WWI + WWF) * 2;
  const bool preall = (off + 12*wLayerBytes + 65536 <= ws_size);
  const int NL = preall ? 12 : 1;
  u16* wqkvB = (u16*)take(WQKV*2*NL);
  u16* woB   = (u16*)take(WWO*2*NL);
  u16* wiB   = (u16*)take(WWI*2*NL);
  u16* wfB   = (u16*)take(WWF*2*NL);

  ConvP cp{Wq, Wk, Wv, Wo, Wi, Wf, wqkvB, woB, wiB, wfB,
           preall ? (long)WQKV : 0, preall ? (long)WWO : 0,
           preall ? (long)WWI : 0, preall ? (long)WWF : 0};

  embed_ln<<<2048, 256, 0, stream>>>(ids, we, pe, te, eg, ebb, hF, hB);
  if (preall) conv_weights<<<12*1728, 256, 0, stream>>>(cp, 0);

  for (int l = 0; l < 12; ++l) {
    if (!preall) conv_weights<<<1728, 256, 0, stream>>>(cp, l);
    const u16* wqkv_l = wqkvB + (size_t)l*cp.doqkv;
    const u16* wo_l   = woB   + (size_t)l*cp.doo;
    const u16* wi_l   = wiB   + (size_t)l*cp.doi;
    const u16* wf_l   = wfB   + (size_t)l*cp.dof;

    GP pq{}; pq.A = hB; pq.B = wqkv_l; pq.K = 768; pq.N = 2304;
    pq.bq = bq + l*768; pq.bk = bk + l*768; pq.bv = bv + l*768;
    pq.qO = qB; pq.kO = kB; pq.vO = vB;
    gemm_bt<64,128,4,0,1><<<dim3(18,32,1), 256, 0, stream>>>(pq);

    if (l == 6) {
      flash_attn<1><<<dim3(48,16), 256, 0, stream>>>(qB, kB, vB, amask, ctxB,
                                                     krel + 6*50*64, rel, wbF);
      rat_apply<<<768, 256, 0, stream>>>(wbF, vrel + 6*50*64, ctxB);
    } else {
      flash_attn<0><<<dim3(48,16), 256, 0, stream>>>(qB, kB, vB, amask, ctxB,
                                                     nullptr, nullptr, nullptr);
    }

    GP po{}; po.A = ctxB; po.B = wo_l; po.K = 768; po.N = 768; po.sOut = PSTRIDE;
    po.outF = tmpF;
    gemm_bt<64,128,4,2,2><<<dim3(6,32,2), 256, 0, stream>>>(po);
    ln_fused<<<2048, 256, 0, stream>>>(tmpF, tmpF + PSTRIDE, nullptr, nullptr, 2,
                                       bo + l*768, hF, g1 + l*768, b1 + l*768, atF, atB);

    GP pf1{}; pf1.A = atB; pf1.B = wi_l; pf1.K = 768; pf1.N = 3072;
    pf1.bias = bi + (size_t)l*3072; pf1.outB = ffB;
    gemm_bt<64,128,4,3,1><<<dim3(24,32,1), 256, 0, stream>>>(pf1);

    GP pf2{}; pf2.A = ffB; pf2.B = wf_l; pf2.K = 3072; pf2.N = 768; pf2.sOut = PSTRIDE;
    pf2.outF = tmpF;
    gemm_bt<64,128,4,2,4><<<dim3(6,32,4), 256, 0, stream>>>(pf2);
    ln_fused<<<2048, 256, 0, stream>>>(tmpF, tmpF + PSTRIDE, tmpF + 2*PSTRIDE, tmpF + 3*PSTRIDE, 4,
                                       bfp + l*768, atF, g2 + l*768, b2 + l*768, hF, hB);
  }

  copy_out<<<1536, 256, 0, stream>>>(hF, (float*)d_out);
  pooler_k<<<4, 256, 0, stream>>>(hF, pwp, pbp, (float*)d_out + (size_t)2048*768);
}

// Round 14
// 1661.148 us; speedup vs baseline: 1.0589x; 1.0589x over previous
//
#include <hip/hip_runtime.h>
#include <math.h>

typedef unsigned short u16;
typedef unsigned int   u32;
typedef __bf16  bf16x8 __attribute__((ext_vector_type(8)));
typedef float   f32x4  __attribute__((ext_vector_type(4)));
typedef u16     u16x8  __attribute__((ext_vector_type(8)));
typedef u16     u16x4  __attribute__((ext_vector_type(4)));

__device__ __forceinline__ u16 f2bf(float f) {
  u32 u = __builtin_bit_cast(u32, f);
  u32 r = (u + 0x7fffu + ((u >> 16) & 1u)) >> 16;
  return (u16)r;
}
__device__ __forceinline__ float bf2f(u16 h) {
  u32 u = ((u32)h) << 16;
  return __builtin_bit_cast(float, u);
}
__device__ __forceinline__ void gload16(const void* g, void* l) {
  __builtin_amdgcn_global_load_lds((const __attribute__((address_space(1))) void*)g,
                                   (__attribute__((address_space(3))) void*)l, 16, 0, 0);
}
__device__ __forceinline__ bf16x8 ld_bf8(const u16* p) {
  u16x8 v = *(const u16x8*)p;
  return __builtin_bit_cast(bf16x8, v);
}
__device__ __forceinline__ f32x4 mfma16(bf16x8 a, bf16x8 b, f32x4 c) {
  return __builtin_amdgcn_mfma_f32_16x16x32_bf16(a, b, c, 0, 0, 0);
}

// ---------------------------------------------------------------- weights
struct ConvP {
  const float *wq, *wk, *wv, *wo, *wi, *wf;   // layer-0 bases
  u16 *oqkv, *oo, *oi, *of;                   // dst bases
  long doqkv, doo, doi, dof;                  // dst layer strides (elements; 0 = rotating)
};
// transpose+convert f32 [K,N] -> bf16 [N,K]; 64x64 tiles, 1728 tiles/layer.
// Read: float4 (256B runs). Write: u16x8 (full 128B lines per 8-lane group).
__global__ __launch_bounds__(256) void conv_weights(ConvP p, int l0) {
  int l = l0 + blockIdx.x / 1728;
  int t = blockIdx.x % 1728;
  const float* in; u16* out; int K, N, tn, tk;
  if (t < 432) { int wh = t / 144, tt = t % 144;
    in = (wh==0 ? p.wq : (wh==1 ? p.wk : p.wv)) + (size_t)l*768*768;
    out = p.oqkv + (size_t)l*p.doqkv + (size_t)wh * 768 * 768;
    K = 768; N = 768; tn = tt % 12; tk = tt / 12;
  } else if (t < 576) { int tt = t - 432;
    in = p.wo + (size_t)l*768*768; out = p.oo + (size_t)l*p.doo;
    K=768;  N=768;  tn=tt%12; tk=tt/12;
  } else if (t < 1152) { int tt = t - 576;
    in = p.wi + (size_t)l*768*3072; out = p.oi + (size_t)l*p.doi;
    K=768;  N=3072; tn=tt%48; tk=tt/48;
  } else { int tt = t - 1152;
    in = p.wf + (size_t)l*768*3072; out = p.of + (size_t)l*p.dof;
    K=3072; N=768;  tn=tt%12; tk=tt/12;
  }
  int n0 = tn*64, k0 = tk*64;
  __shared__ float tile[64][65];
  int tid = threadIdx.x;
  int tx = tid & 15, ry = tid >> 4;     // read: 16 float4-cols x 16 rows/pass
  #pragma unroll
  for (int j = 0; j < 4; ++j) {
    int kk = j*16 + ry;
    float4 rv = *(const float4*)(in + (size_t)(k0 + kk) * N + n0 + tx*4);
    tile[kk][tx*4+0] = rv.x; tile[kk][tx*4+1] = rv.y;
    tile[kk][tx*4+2] = rv.z; tile[kk][tx*4+3] = rv.w;
  }
  __syncthreads();
  int tx2 = tid & 7, ry2 = tid >> 3;    // write: 8 u16x8-cols x 32 rows/pass
  #pragma unroll
  for (int j = 0; j < 2; ++j) {
    int nn = j*32 + ry2;
    u16x8 ov;
    #pragma unroll
    for (int c = 0; c < 8; ++c) ov[c] = f2bf(tile[tx2*8+c][nn]);
    *(u16x8*)(out + (size_t)(n0 + nn) * K + k0 + tx2*8) = ov;
  }
}

// ---------------------------------------------------------------- GEMM (A[M,K] bf16 x B^T[N,K] bf16)
struct GP {
  const u16* A; const u16* B;
  int K, N;
  long sA, sB, sOut;
  const float* bias; const float* res;
  float* outF; u16* outB;
  const float* bq; const float* bk; const float* bv;
  u16* qO; u16* kO; u16* vO;
};

// EPI: 0=QKV scatter, 2=f32 partial, 3=gelu->bf16
template<int BM, int BN, int WAVES, int EPI, int KS>
__global__ __launch_bounds__(WAVES*64) void gemm_bt(GP p) {
  constexpr int THREADS = WAVES * 64;
  constexpr int WC = WAVES / 2;
  constexpr int WM = BM / 2, WN = BN / WC, MR = WM / 16, NR = WN / 16;
  constexpr int AIT = BM * 64 / (THREADS * 8);
  constexpr int BIT = BN * 64 / (THREADS * 8);
  const int tid = threadIdx.x;
  const int wave = tid >> 6, lane = tid & 63;
  const int wr = wave / WC, wc = wave % WC;
  const int wm0 = wr * WM, wn0 = wc * WN;
  const int bn = blockIdx.x, bm = blockIdx.y, bz = blockIdx.z;
  const int K = p.K;
  const int kLen = K / KS;
  const int kBeg = (KS > 1) ? bz * kLen : 0;
  const u16* A  = p.A + ((KS > 1) ? 0 : (size_t)bz * p.sA);
  const u16* Bp = p.B + ((KS > 1) ? 0 : (size_t)bz * p.sB);
  const int rowA0 = bm * BM, colB0 = bn * BN;

  __shared__ __align__(16) u16 lds[(BM + BN) * 64];
  u16* Al = lds; u16* Bl = lds + BM * 64;

  f32x4 acc[MR][NR];
  #pragma unroll
  for (int i = 0; i < MR; ++i)
    #pragma unroll
    for (int j = 0; j < NR; ++j) acc[i][j] = f32x4{0.f,0.f,0.f,0.f};

  for (int kt = kBeg; kt < kBeg + kLen; kt += 64) {
    #pragma unroll
    for (int it = 0; it < AIT; ++it) {
      int e = tid * 8 + it * THREADS * 8;
      gload16(A + (size_t)(rowA0 + (e >> 6)) * K + kt + (e & 63), Al + e);
    }
    #pragma unroll
    for (int it = 0; it < BIT; ++it) {
      int e = tid * 8 + it * THREADS * 8;
      gload16(Bp + (size_t)(colB0 + (e >> 6)) * K + kt + (e & 63), Bl + e);
    }
    __syncthreads();
    #pragma unroll
    for (int ks = 0; ks < 2; ++ks) {
      bf16x8 av[MR]; bf16x8 bw[NR];
      #pragma unroll
      for (int mf = 0; mf < MR; ++mf)
        av[mf] = ld_bf8(Al + (wm0 + mf*16 + (lane&15))*64 + ks*32 + (lane>>4)*8);
      #pragma unroll
      for (int nf = 0; nf < NR; ++nf)
        bw[nf] = ld_bf8(Bl + (wn0 + nf*16 + (lane&15))*64 + ks*32 + (lane>>4)*8);
      #pragma unroll
      for (int mf = 0; mf < MR; ++mf)
        #pragma unroll
        for (int nf = 0; nf < NR; ++nf)
          acc[mf][nf] = mfma16(av[mf], bw[nf], acc[mf][nf]);
    }
    __syncthreads();
  }

  #pragma unroll
  for (int mf = 0; mf < MR; ++mf) {
    #pragma unroll
    for (int nf = 0; nf < NR; ++nf) {
      int col = colB0 + wn0 + nf*16 + (lane & 15);
      #pragma unroll
      for (int reg = 0; reg < 4; ++reg) {
        int row = rowA0 + wm0 + mf*16 + (lane >> 4)*4 + reg;
        float v = acc[mf][nf][reg];
        if constexpr (EPI == 0) { // QKV scatter
          int wh = col / 768, cc = col % 768;
          int hh = cc >> 6, d = col & 63;
          int b = row >> 9, s = row & 511;
          const float* bias = wh==0 ? p.bq : (wh==1 ? p.bk : p.bv);
          u16 o = f2bf(v + bias[cc]);
          if (wh == 0)      p.qO[((((size_t)b*12 + hh)*512 + s) << 6) + d] = o;
          else if (wh == 1) p.kO[((((size_t)b*12 + hh)*512 + s) << 6) + d] = o;
          else              p.vO[((((size_t)b*12 + hh)*64  + d) << 9) + s] = o;
        } else if constexpr (EPI == 2) { // raw f32 partial
          p.outF[(size_t)bz * p.sOut + (size_t)row * p.N + col] = v;
        } else { // gelu -> bf16
          float xg = v + p.bias[col];
          float gg = 0.5f * xg * (1.f + erff(xg * 0.70710678118f));
          p.outB[(size_t)row * p.N + col] = f2bf(gg);
        }
      }
    }
  }
}

// ---------------------------------------------------------------- flash attention v4 (r12 structure: staged+swizzled)
// block: (head, 32 q-rows), 4 waves (wr=row-half, wc=t-half). K/V staged to LDS
// with XOR swizzle; RAT qr table computed in-kernel via MFMA.
template<int RAT>
__global__ __launch_bounds__(256) void flash_attn(
    const u16* __restrict__ q, const u16* __restrict__ k, const u16* __restrict__ v,
    const int* __restrict__ mask, u16* __restrict__ ctx,
    const float* __restrict__ kr, const int* __restrict__ rel,
    float* __restrict__ wbins) {
  const int head = blockIdx.x;   // 0..47 (48 % 8 == 0 -> same head on one XCD)
  const int bm = blockIdx.y;     // 0..15
  const int b = head / 12, hh = head % 12;
  const int tid = threadIdx.x, wave = tid >> 6, lane = tid & 63;
  const int wr = wave >> 1, wc = wave & 1;
  const int row0 = bm * 32;
  const u16* qb = q + (size_t)head * 512 * 64;
  const u16* kb = k + (size_t)head * 512 * 64;
  const u16* vb = v + (size_t)head * 64 * 512;   // [d][t]

  __shared__ __align__(16) u16 Kl[2][64*64];     // [t-half][tile]
  __shared__ __align__(16) u16 Vl[2][64*64];
  __shared__ __align__(16) u16 pw[4][16*72];     // P bounce; aliased: kr bf16 (RAT init), f32 merge buf
  __shared__ float em_lds[512];
  __shared__ float mlb[2][16][2];
  __shared__ float qlds[RAT ? 32 : 1][RAT ? 52 : 1];
  __shared__ float wlds[RAT ? 2 : 1][RAT ? 32 : 1][RAT ? 50 : 1];
  __shared__ float scl[RAT ? 2 : 1][RAT ? 32 : 1];
  __shared__ float aex[RAT ? 32 : 1][RAT ? 3 : 1];

  for (int i = tid; i < 512; i += 256)
    em_lds[i] = -10000.f * (1.f - (float)mask[b*512 + i]);
  u16* Krl = (u16*)pw;                          // 64x64 bf16 = 8KB <= pw 9KB
  if constexpr (RAT) {
    for (int i = tid; i < 2*32*50; i += 256) ((float*)wlds)[i] = 0.f;
    for (int i = tid; i < 64*64; i += 256) {
      int r = i >> 6, c = i & 63;
      Krl[i] = (r < 50) ? f2bf(kr[r*64 + c]) : (u16)0;
    }
  }

  // Q fragments direct from global (L2-resident)
  const int qrow = row0 + wr*16 + (lane & 15);
  const int g = lane >> 4;
  bf16x8 qf[2];
  qf[0] = ld_bf8(qb + (size_t)qrow*64 +      g*8);
  qf[1] = ld_bf8(qb + (size_t)qrow*64 + 32 + g*8);
  __syncthreads();   // em_lds (+Krl, wlds) ready

  if constexpr (RAT) {
    // qr[rl][rr] = q-row . kr-row, via 4 MFMAs per wave (wc owns rr-half)
    #pragma unroll
    for (int nf = 0; nf < 2; ++nf) {
      f32x4 a = f32x4{0.f,0.f,0.f,0.f};
      #pragma unroll
      for (int ks = 0; ks < 2; ++ks) {
        bf16x8 krf = ld_bf8(Krl + (wc*32 + nf*16 + (lane&15))*64 + ks*32 + g*8);
        a = mfma16(qf[ks], krf, a);
      }
      int rr = wc*32 + nf*16 + (lane & 15);
      if (rr < 50) {
        #pragma unroll
        for (int reg = 0; reg < 4; ++reg)
          qlds[wr*16 + g*4 + reg][rr] = a[reg];
      }
    }
    __syncthreads();   // qlds ready; pw (Krl) free for P tiles
  }

  f32x4 ctxacc[4];
  #pragma unroll
  for (int nf = 0; nf < 4; ++nf) ctxacc[nf] = f32x4{0.f,0.f,0.f,0.f};
  float mrun[4], lrun[4];
  #pragma unroll
  for (int r = 0; r < 4; ++r) { mrun[r] = -3.0e38f; lrun[r] = 0.f; }

  for (int it = 0; it < 4; ++it) {
    // stage both halves' K/V tiles; source pre-swizzled (col16 ^= row&7)
    #pragma unroll
    for (int j = 0; j < 2; ++j) {
      int s = j*256 + tid;
      int prow = s >> 3, c16 = (s & 7) ^ (prow & 7);
      int t0a = it*64, t0b = 256 + it*64;
      gload16(kb + (size_t)(t0a + prow)*64 + c16*8, Kl[0] + s*8);
      gload16(kb + (size_t)(t0b + prow)*64 + c16*8, Kl[1] + s*8);
      gload16(vb + (size_t)prow*512 + t0a + c16*8, Vl[0] + s*8);
      gload16(vb + (size_t)prow*512 + t0b + c16*8, Vl[1] + s*8);
    }
    __syncthreads();
    const int tbase = wc*256 + it*64;

    // S = Q K^T (swizzled K reads)
    f32x4 s[4];
    #pragma unroll
    for (int nf = 0; nf < 4; ++nf) s[nf] = f32x4{0.f,0.f,0.f,0.f};
    #pragma unroll
    for (int ks = 0; ks < 2; ++ks)
      #pragma unroll
      for (int nf = 0; nf < 4; ++nf) {
        int row = nf*16 + (lane & 15);
        int c16 = (ks*4 + g) ^ (row & 7);
        bf16x8 kf = ld_bf8(Kl[wc] + row*64 + c16*8);
        s[nf] = mfma16(qf[ks], kf, s[nf]);
      }

    u32 rr4[RAT ? 4 : 1];
    if constexpr (RAT) {
      #pragma unroll
      for (int nf = 0; nf < 4; ++nf) {
        int tt = tbase + nf*16 + (lane & 15);
        u32 pack = 0;
        #pragma unroll
        for (int reg = 0; reg < 4; ++reg) {
          int rl = wr*16 + g*4 + reg;
          int rr = rel[((size_t)(b*512 + row0 + rl))*512 + tt];
          pack |= (u32)rr << (8*reg);
          s[nf][reg] += qlds[rl][rr];
        }
        rr4[nf] = pack;
      }
    }

    float em4[4];
    #pragma unroll
    for (int nf = 0; nf < 4; ++nf) em4[nf] = em_lds[tbase + nf*16 + (lane & 15)];

    float scale_[4];
    #pragma unroll
    for (int reg = 0; reg < 4; ++reg) {
      float pm = -3.0e38f;
      #pragma unroll
      for (int nf = 0; nf < 4; ++nf) {
        s[nf][reg] = s[nf][reg]*0.125f + em4[nf];
        pm = fmaxf(pm, s[nf][reg]);
      }
      #pragma unroll
      for (int o = 1; o < 16; o <<= 1) pm = fmaxf(pm, __shfl_xor(pm, o));
      float mnew = fmaxf(mrun[reg], pm);
      float sc = __expf(mrun[reg] - mnew);
      mrun[reg] = mnew;
      scale_[reg] = sc;
      float lsum = 0.f;
      #pragma unroll
      for (int nf = 0; nf < 4; ++nf) {
        float e = __expf(s[nf][reg] - mnew);
        s[nf][reg] = e;
        lsum += e;
      }
      #pragma unroll
      for (int o = 1; o < 16; o <<= 1) lsum += __shfl_xor(lsum, o);
      lrun[reg] = lrun[reg]*sc + lsum;
      if constexpr (RAT) {
        if ((lane & 15) == 0) scl[wc][wr*16 + g*4 + reg] = sc;
      }
    }

    if constexpr (RAT) {
      for (int i = lane; i < 16*50; i += 64) {
        int r = i / 50;
        wlds[wc][wr*16 + r][i % 50] *= scl[wc][wr*16 + r];
      }
      #pragma unroll
      for (int nf = 0; nf < 4; ++nf)
        #pragma unroll
        for (int reg = 0; reg < 4; ++reg) {
          int rl = wr*16 + g*4 + reg;
          int rr = (rr4[nf] >> (8*reg)) & 255;
          atomicAdd(&wlds[wc][rl][rr], s[nf][reg]);
        }
    }

    // P -> wave-private LDS (in-order DS per wave; no barrier)
    #pragma unroll
    for (int nf = 0; nf < 4; ++nf)
      #pragma unroll
      for (int reg = 0; reg < 4; ++reg) {
        int qq = g*4 + reg;
        pw[wave][qq*72 + nf*16 + (lane & 15)] = f2bf(s[nf][reg]);
      }

    // rescale ctx, then PV (swizzled V reads)
    #pragma unroll
    for (int nf = 0; nf < 4; ++nf)
      #pragma unroll
      for (int reg = 0; reg < 4; ++reg)
        ctxacc[nf][reg] *= scale_[reg];
    #pragma unroll
    for (int ks = 0; ks < 2; ++ks) {
      bf16x8 pf = ld_bf8(pw[wave] + (lane & 15)*72 + ks*32 + g*8);
      #pragma unroll
      for (int nf = 0; nf < 4; ++nf) {
        int row = nf*16 + (lane & 15);
        int c16 = (ks*4 + g) ^ (row & 7);
        bf16x8 vf = ld_bf8(Vl[wc] + row*64 + c16*8);
        ctxacc[nf] = mfma16(pf, vf, ctxacc[nf]);
      }
    }
    __syncthreads();   // retire reads before next-iteration overwrite
  }

  // ---- merge the two t-half partials (pw reused as f32 [32][66])
  float* mergeF = (float*)pw;
  if (wc == 1) {
    #pragma unroll
    for (int nf = 0; nf < 4; ++nf)
      #pragma unroll
      for (int reg = 0; reg < 4; ++reg)
        mergeF[(wr*16 + g*4 + reg)*66 + nf*16 + (lane & 15)] = ctxacc[nf][reg];
    if ((lane & 15) == 0) {
      #pragma unroll
      for (int reg = 0; reg < 4; ++reg) {
        mlb[wr][g*4 + reg][0] = mrun[reg];
        mlb[wr][g*4 + reg][1] = lrun[reg];
      }
    }
  }
  __syncthreads();
  if (wc == 0) {
    float a1[4], a2[4], linv[4];
    #pragma unroll
    for (int reg = 0; reg < 4; ++reg) {
      int r = g*4 + reg;
      float m2 = mlb[wr][r][0], l2 = mlb[wr][r][1];
      float mn = fmaxf(mrun[reg], m2);
      a1[reg] = __expf(mrun[reg] - mn);
      a2[reg] = __expf(m2 - mn);
      linv[reg] = 1.f / (lrun[reg]*a1[reg] + l2*a2[reg]);
      if constexpr (RAT) {
        if ((lane & 15) == 0) {
          aex[wr*16 + r][0] = a1[reg];
          aex[wr*16 + r][1] = a2[reg];
          aex[wr*16 + r][2] = linv[reg];
        }
      }
    }
    #pragma unroll
    for (int nf = 0; nf < 4; ++nf)
      #pragma unroll
      for (int reg = 0; reg < 4; ++reg) {
        int r = wr*16 + g*4 + reg;
        int qg = row0 + r;
        int d = nf*16 + (lane & 15);
        float v2 = mergeF[r*66 + d];
        ctx[((size_t)(b*512 + qg))*768 + hh*64 + d] =
            f2bf((ctxacc[nf][reg]*a1[reg] + v2*a2[reg]) * linv[reg]);
      }
  }
  if constexpr (RAT) {
    __syncthreads();
    for (int i = tid; i < 32*50; i += 256) {
      int sr = i / 50, rr = i % 50;
      wbins[((size_t)head*512 + row0 + sr)*50 + rr] =
          (wlds[0][sr][rr]*aex[sr][0] + wlds[1][sr][rr]*aex[sr][1]) * aex[sr][2];
    }
  }
}

// ---------------------------------------------------------------- RAT apply (layer 6)
__global__ __launch_bounds__(256) void rat_apply(const float* __restrict__ wbins,
    const float* __restrict__ vr, u16* __restrict__ ctx) {
  __shared__ float vrl[50*64];
  __shared__ float wl[32*50];
  int tid = threadIdx.x;
  int rows0 = blockIdx.x * 32;
  for (int i = tid; i < 50*64; i += 256) vrl[i] = vr[i];
  for (int i = tid; i < 32*50; i += 256) wl[i] = wbins[(size_t)rows0*50 + i];
  __syncthreads();
  int wave = tid >> 6, lane = tid & 63;
  #pragma unroll
  for (int i = 0; i < 8; ++i) {
    int r = wave*8 + i;
    size_t idx = (size_t)rows0 + r;
    float acc = 0.f;
    #pragma unroll
    for (int j = 0; j < 50; ++j) acc += wl[r*50 + j] * vrl[j*64 + lane];
    int s = (int)(idx & 511); size_t bh = idx >> 9;
    int b = (int)(bh / 12), hh = (int)(bh % 12);
    u16* cp = ctx + ((size_t)(b*512 + s))*768 + hh*64 + lane;
    *cp = f2bf(bf2f(*cp) + acc);
  }
}

// ---------------------------------------------------------------- embeddings + LN
__global__ __launch_bounds__(256) void embed_ln(const int* __restrict__ ids,
    const float* __restrict__ we, const float* __restrict__ pe, const float* __restrict__ te,
    const float* __restrict__ g, const float* __restrict__ b,
    float* __restrict__ hF, u16* __restrict__ hB) {
  int row = blockIdx.x, tid = threadIdx.x;
  int s = row & 511;
  int id = ids[row];
  float x[3];
  #pragma unroll
  for (int j = 0; j < 3; ++j) {
    int d = tid + j*256;
    x[j] = we[(size_t)id*768 + d] + pe[(size_t)s*768 + d] + te[d];
  }
  __shared__ float red[4];
  float sm = x[0] + x[1] + x[2];
  #pragma unroll
  for (int o = 32; o; o >>= 1) sm += __shfl_xor(sm, o);
  if (!(tid & 63)) red[tid >> 6] = sm;
  __syncthreads();
  float mean = (red[0]+red[1]+red[2]+red[3]) * (1.f/768.f);
  __syncthreads();
  float q = 0.f;
  #pragma unroll
  for (int j = 0; j < 3; ++j) { float d = x[j] - mean; q += d*d; }
  #pragma unroll
  for (int o = 32; o; o >>= 1) q += __shfl_xor(q, o);
  if (!(tid & 63)) red[tid >> 6] = q;
  __syncthreads();
  float inv = rsqrtf((red[0]+red[1]+red[2]+red[3]) * (1.f/768.f) + 1e-12f);
  #pragma unroll
  for (int j = 0; j < 3; ++j) {
    int d = tid + j*256;
    float y = (x[j] - mean) * inv * g[d] + b[d];
    hF[(size_t)row*768 + d] = y;
    hB[(size_t)row*768 + d] = f2bf(y);
  }
}

// LN over (p0[+p1][+p2][+p3]) + bias + res
__global__ __launch_bounds__(256) void ln_fused(const float* __restrict__ p0,
    const float* __restrict__ p1, const float* __restrict__ p2, const float* __restrict__ p3,
    int np, const float* __restrict__ bias, const float* __restrict__ res,
    const float* __restrict__ g, const float* __restrict__ b,
    float* __restrict__ oF, u16* __restrict__ oB) {
  int row = blockIdx.x, tid = threadIdx.x;
  size_t base = (size_t)row * 768;
  float v[3];
  #pragma unroll
  for (int j = 0; j < 3; ++j) {
    int d = tid + j*256;
    float x = p0[base + d];
    if (np > 1) x += p1[base + d];
    if (np > 2) x += p2[base + d];
    if (np > 3) x += p3[base + d];
    v[j] = x + bias[d] + res[base + d];
  }
  __shared__ float red[4];
  float sm = v[0] + v[1] + v[2];
  #pragma unroll
  for (int o = 32; o; o >>= 1) sm += __shfl_xor(sm, o);
  if (!(tid & 63)) red[tid >> 6] = sm;
  __syncthreads();
  float mean = (red[0]+red[1]+red[2]+red[3]) * (1.f/768.f);
  __syncthreads();
  float q = 0.f;
  #pragma unroll
  for (int j = 0; j < 3; ++j) { float d = v[j] - mean; q += d*d; }
  #pragma unroll
  for (int o = 32; o; o >>= 1) q += __shfl_xor(q, o);
  if (!(tid & 63)) red[tid >> 6] = q;
  __syncthreads();
  float inv = rsqrtf((red[0]+red[1]+red[2]+red[3]) * (1.f/768.f) + 1e-12f);
  #pragma unroll
  for (int j = 0; j < 3; ++j) {
    int d = tid + j*256;
    float y = (v[j] - mean) * inv * g[d] + b[d];
    oF[base + d] = y;
    oB[base + d] = f2bf(y);
  }
}

// ---------------------------------------------------------------- tail
__global__ __launch_bounds__(256) void pooler_k(const float* __restrict__ h,
    const float* __restrict__ w, const float* __restrict__ bias, float* __restrict__ out) {
  int b = blockIdx.x, tid = threadIdx.x;
  __shared__ float hr[768];
  for (int i = tid; i < 768; i += 256) hr[i] = h[((size_t)b*512)*768 + i];
  __syncthreads();
  float a0 = 0.f, a1 = 0.f, a2 = 0.f;
  for (int kk = 0; kk < 768; ++kk) {
    float hv = hr[kk];
    const float* wr = w + (size_t)kk*768;
    a0 += hv * wr[tid]; a1 += hv * wr[tid+256]; a2 += hv * wr[tid+512];
  }
  out[(size_t)b*768 + tid]       = tanhf(a0 + bias[tid]);
  out[(size_t)b*768 + tid + 256] = tanhf(a1 + bias[tid+256]);
  out[(size_t)b*768 + tid + 512] = tanhf(a2 + bias[tid+512]);
}

// ---------------------------------------------------------------- host
extern "C" void kernel_launch(void* const* d_in, const int* in_sizes, int n_in,
                              void* d_out, int out_size, void* d_ws, size_t ws_size,
                              hipStream_t stream) {
  const int*   ids   = (const int*)d_in[0];
  const int*   rel   = (const int*)d_in[1];
  const int*   amask = (const int*)d_in[2];
  const float* we    = (const float*)d_in[3];
  const float* pe    = (const float*)d_in[4];
  const float* te    = (const float*)d_in[5];
  const float* eg    = (const float*)d_in[6];
  const float* ebb   = (const float*)d_in[7];
  const float* Wq    = (const float*)d_in[8];
  const float* bq    = (const float*)d_in[9];
  const float* Wk    = (const float*)d_in[10];
  const float* bk    = (const float*)d_in[11];
  const float* Wv    = (const float*)d_in[12];
  const float* bv    = (const float*)d_in[13];
  const float* Wo    = (const float*)d_in[14];
  const float* bo    = (const float*)d_in[15];
  const float* g1    = (const float*)d_in[16];
  const float* b1    = (const float*)d_in[17];
  const float* Wi    = (const float*)d_in[18];
  const float* bi    = (const float*)d_in[19];
  const float* Wf    = (const float*)d_in[20];
  const float* bfp   = (const float*)d_in[21];
  const float* g2    = (const float*)d_in[22];
  const float* b2    = (const float*)d_in[23];
  const float* krel  = (const float*)d_in[24];
  const float* vrel  = (const float*)d_in[25];
  const float* pwp   = (const float*)d_in[26];
  const float* pbp   = (const float*)d_in[27];
  (void)in_sizes; (void)n_in; (void)out_size;

  char* ws = (char*)d_ws;
  size_t off = 0;
  auto take = [&](size_t bytes) { char* p = ws + off; off += (bytes + 255) & ~(size_t)255; return p; };
  float* hF   = (float*)take((size_t)2048*768*4);
  u16*   hB   = (u16*)take((size_t)2048*768*2);
  float* atF  = (float*)take((size_t)2048*768*4);
  u16*   atB  = (u16*)take((size_t)2048*768*2);
  u16*   qB   = (u16*)take((size_t)2048*768*2);
  u16*   kB   = (u16*)take((size_t)2048*768*2);
  u16*   vB   = (u16*)take((size_t)2048*768*2);
  u16*   ctxB = (u16*)take((size_t)2048*768*2);
  float* tmpF = (float*)take((size_t)4*2048*768*4);   // 4 split-K partials
  u16*   ffB  = (u16*)take((size_t)2048*3072*2);
  float* wbF  = (float*)take((size_t)24576*50*4);
  const size_t PSTRIDE = (size_t)2048*768;

  // weight buffers: pre-convert all 12 layers in one launch if workspace allows
  const size_t WQKV = (size_t)2304*768, WWO = (size_t)768*768;
  const size_t WWI = (size_t)768*3072, WWF = (size_t)3072*768;
  const size_t wLayerBytes = (WQKV + WWO + WWI + WWF) * 2;
  const bool preall = (off + 12*wLayerBytes + 65536 <= ws_size);
  const int NL = preall ? 12 : 1;
  u16* wqkvB = (u16*)take(WQKV*2*NL);
  u16* woB   = (u16*)take(WWO*2*NL);
  u16* wiB   = (u16*)take(WWI*2*NL);
  u16* wfB   = (u16*)take(WWF*2*NL);

  ConvP cp{Wq, Wk, Wv, Wo, Wi, Wf, wqkvB, woB, wiB, wfB,
           preall ? (long)WQKV : 0, preall ? (long)WWO : 0,
           preall ? (long)WWI : 0, preall ? (long)WWF : 0};

  embed_ln<<<2048, 256, 0, stream>>>(ids, we, pe, te, eg, ebb, hF, hB);
  if (preall) conv_weights<<<12*1728, 256, 0, stream>>>(cp, 0);

  for (int l = 0; l < 12; ++l) {
    if (!preall) conv_weights<<<1728, 256, 0, stream>>>(cp, l);
    const u16* wqkv_l = wqkvB + (size_t)l*cp.doqkv;
    const u16* wo_l   = woB   + (size_t)l*cp.doo;
    const u16* wi_l   = wiB   + (size_t)l*cp.doi;
    const u16* wf_l   = wfB   + (size_t)l*cp.dof;

    GP pq{}; pq.A = hB; pq.B = wqkv_l; pq.K = 768; pq.N = 2304;
    pq.bq = bq + l*768; pq.bk = bk + l*768; pq.bv = bv + l*768;
    pq.qO = qB; pq.kO = kB; pq.vO = vB;
    gemm_bt<64,128,4,0,1><<<dim3(18,32,1), 256, 0, stream>>>(pq);

    if (l == 6) {
      flash_attn<1><<<dim3(48,16), 256, 0, stream>>>(qB, kB, vB, amask, ctxB,
                                                     krel + 6*50*64, rel, wbF);
      rat_apply<<<768, 256, 0, stream>>>(wbF, vrel + 6*50*64, ctxB);
    } else {
      flash_attn<0><<<dim3(48,16), 256, 0, stream>>>(qB, kB, vB, amask, ctxB,
                                                     nullptr, nullptr, nullptr);
    }

    GP po{}; po.A = ctxB; po.B = wo_l; po.K = 768; po.N = 768; po.sOut = PSTRIDE;
    po.outF = tmpF;
    gemm_bt<64,128,4,2,2><<<dim3(6,32,2), 256, 0, stream>>>(po);
    ln_fused<<<2048, 256, 0, stream>>>(tmpF, tmpF + PSTRIDE, nullptr, nullptr, 2,
                                       bo + l*768, hF, g1 + l*768, b1 + l*768, atF, atB);

    GP pf1{}; pf1.A = atB; pf1.B = wi_l; pf1.K = 768; pf1.N = 3072;
    pf1.bias = bi + (size_t)l*3072; pf1.outB = ffB;
    gemm_bt<64,128,4,3,1><<<dim3(24,32,1), 256, 0, stream>>>(pf1);

    GP pf2{}; pf2.A = ffB; pf2.B = wf_l; pf2.K = 3072; pf2.N = 768; pf2.sOut = PSTRIDE;
    pf2.outF = tmpF;
    gemm_bt<64,128,4,2,4><<<dim3(6,32,4), 256, 0, stream>>>(pf2);
    // final layer: write normalized h directly into d_out (skip copy kernel)
    float* houtF = (l == 11) ? (float*)d_out : hF;
    ln_fused<<<2048, 256, 0, stream>>>(tmpF, tmpF + PSTRIDE, tmpF + 2*PSTRIDE, tmpF + 3*PSTRIDE, 4,
                                       bfp + l*768, atF, g2 + l*768, b2 + l*768, houtF, hB);
  }

  pooler_k<<<4, 256, 0, stream>>>((const float*)d_out, pwp, pbp, (float*)d_out + (size_t)2048*768);
}

// Round 15
// 1631.063 us; speedup vs baseline: 1.0784x; 1.0184x over previous
//
#include <hip/hip_runtime.h>
#include <math.h>

typedef unsigned short u16;
typedef unsigned int   u32;
typedef __bf16  bf16x8 __attribute__((ext_vector_type(8)));
typedef float   f32x4  __attribute__((ext_vector_type(4)));
typedef u16     u16x8  __attribute__((ext_vector_type(8)));
typedef u16     u16x4  __attribute__((ext_vector_type(4)));

__device__ __forceinline__ u16 f2bf(float f) {
  u32 u = __builtin_bit_cast(u32, f);
  u32 r = (u + 0x7fffu + ((u >> 16) & 1u)) >> 16;
  return (u16)r;
}
__device__ __forceinline__ float bf2f(u16 h) {
  u32 u = ((u32)h) << 16;
  return __builtin_bit_cast(float, u);
}
__device__ __forceinline__ void gload16(const void* g, void* l) {
  __builtin_amdgcn_global_load_lds((const __attribute__((address_space(1))) void*)g,
                                   (__attribute__((address_space(3))) void*)l, 16, 0, 0);
}
__device__ __forceinline__ bf16x8 ld_bf8(const u16* p) {
  u16x8 v = *(const u16x8*)p;
  return __builtin_bit_cast(bf16x8, v);
}
__device__ __forceinline__ f32x4 mfma16(bf16x8 a, bf16x8 b, f32x4 c) {
  return __builtin_amdgcn_mfma_f32_16x16x32_bf16(a, b, c, 0, 0, 0);
}

// ---------------------------------------------------------------- weights
struct ConvP {
  const float *wq, *wk, *wv, *wo, *wi, *wf;   // layer-0 bases
  u16 *oqkv, *oo, *oi, *of;                   // dst bases
  long doqkv, doo, doi, dof;                  // dst layer strides (elements)
};
// transpose+convert f32 [K,N] -> bf16 [N,K]; 64x64 tiles, 1728 tiles/layer.
__global__ __launch_bounds__(256) void conv_weights(ConvP p, int l0) {
  int l = l0 + blockIdx.x / 1728;
  int t = blockIdx.x % 1728;
  const float* in; u16* out; int K, N, tn, tk;
  if (t < 432) { int wh = t / 144, tt = t % 144;
    in = (wh==0 ? p.wq : (wh==1 ? p.wk : p.wv)) + (size_t)l*768*768;
    out = p.oqkv + (size_t)l*p.doqkv + (size_t)wh * 768 * 768;
    K = 768; N = 768; tn = tt % 12; tk = tt / 12;
  } else if (t < 576) { int tt = t - 432;
    in = p.wo + (size_t)l*768*768; out = p.oo + (size_t)l*p.doo;
    K=768;  N=768;  tn=tt%12; tk=tt/12;
  } else if (t < 1152) { int tt = t - 576;
    in = p.wi + (size_t)l*768*3072; out = p.oi + (size_t)l*p.doi;
    K=768;  N=3072; tn=tt%48; tk=tt/48;
  } else { int tt = t - 1152;
    in = p.wf + (size_t)l*768*3072; out = p.of + (size_t)l*p.dof;
    K=3072; N=768;  tn=tt%12; tk=tt/12;
  }
  int n0 = tn*64, k0 = tk*64;
  __shared__ float tile[64][65];
  int tid = threadIdx.x;
  int tx = tid & 15, ry = tid >> 4;
  #pragma unroll
  for (int j = 0; j < 4; ++j) {
    int kk = j*16 + ry;
    float4 rv = *(const float4*)(in + (size_t)(k0 + kk) * N + n0 + tx*4);
    tile[kk][tx*4+0] = rv.x; tile[kk][tx*4+1] = rv.y;
    tile[kk][tx*4+2] = rv.z; tile[kk][tx*4+3] = rv.w;
  }
  __syncthreads();
  int tx2 = tid & 7, ry2 = tid >> 3;
  #pragma unroll
  for (int j = 0; j < 2; ++j) {
    int nn = j*32 + ry2;
    u16x8 ov;
    #pragma unroll
    for (int c = 0; c < 8; ++c) ov[c] = f2bf(tile[tx2*8+c][nn]);
    *(u16x8*)(out + (size_t)(n0 + nn) * K + k0 + tx2*8) = ov;
  }
}

// ---------------------------------------------------------------- GEMM (A[M,K] bf16 x B^T[N,K] bf16)
struct GP {
  const u16* A; const u16* B;
  int K, N;
  long sA, sB, sOut;
  const float* bias; const float* res;
  float* outF; u16* outB;
  const float* bq; const float* bk; const float* bv;
  u16* qO; u16* kO; u16* vO;
};

// EPI: 0=QKV scatter, 2=bf16 partial, 3=gelu->bf16
template<int BM, int BN, int WAVES, int EPI, int KS>
__global__ __launch_bounds__(WAVES*64) void gemm_bt(GP p) {
  constexpr int THREADS = WAVES * 64;
  constexpr int WC = WAVES / 2;
  constexpr int WM = BM / 2, WN = BN / WC, MR = WM / 16, NR = WN / 16;
  constexpr int AIT = BM * 64 / (THREADS * 8);
  constexpr int BIT = BN * 64 / (THREADS * 8);
  const int tid = threadIdx.x;
  const int wave = tid >> 6, lane = tid & 63;
  const int wr = wave / WC, wc = wave % WC;
  const int wm0 = wr * WM, wn0 = wc * WN;
  const int bn = blockIdx.x, bm = blockIdx.y, bz = blockIdx.z;
  const int K = p.K;
  const int kLen = K / KS;
  const int kBeg = (KS > 1) ? bz * kLen : 0;
  const u16* A  = p.A + ((KS > 1) ? 0 : (size_t)bz * p.sA);
  const u16* Bp = p.B + ((KS > 1) ? 0 : (size_t)bz * p.sB);
  const int rowA0 = bm * BM, colB0 = bn * BN;

  __shared__ __align__(16) u16 lds[(BM + BN) * 64];
  u16* Al = lds; u16* Bl = lds + BM * 64;

  f32x4 acc[MR][NR];
  #pragma unroll
  for (int i = 0; i < MR; ++i)
    #pragma unroll
    for (int j = 0; j < NR; ++j) acc[i][j] = f32x4{0.f,0.f,0.f,0.f};

  for (int kt = kBeg; kt < kBeg + kLen; kt += 64) {
    #pragma unroll
    for (int it = 0; it < AIT; ++it) {
      int e = tid * 8 + it * THREADS * 8;
      gload16(A + (size_t)(rowA0 + (e >> 6)) * K + kt + (e & 63), Al + e);
    }
    #pragma unroll
    for (int it = 0; it < BIT; ++it) {
      int e = tid * 8 + it * THREADS * 8;
      gload16(Bp + (size_t)(colB0 + (e >> 6)) * K + kt + (e & 63), Bl + e);
    }
    __syncthreads();
    #pragma unroll
    for (int ks = 0; ks < 2; ++ks) {
      bf16x8 av[MR]; bf16x8 bw[NR];
      #pragma unroll
      for (int mf = 0; mf < MR; ++mf)
        av[mf] = ld_bf8(Al + (wm0 + mf*16 + (lane&15))*64 + ks*32 + (lane>>4)*8);
      #pragma unroll
      for (int nf = 0; nf < NR; ++nf)
        bw[nf] = ld_bf8(Bl + (wn0 + nf*16 + (lane&15))*64 + ks*32 + (lane>>4)*8);
      #pragma unroll
      for (int mf = 0; mf < MR; ++mf)
        #pragma unroll
        for (int nf = 0; nf < NR; ++nf)
          acc[mf][nf] = mfma16(av[mf], bw[nf], acc[mf][nf]);
    }
    __syncthreads();
  }

  #pragma unroll
  for (int mf = 0; mf < MR; ++mf) {
    #pragma unroll
    for (int nf = 0; nf < NR; ++nf) {
      int col = colB0 + wn0 + nf*16 + (lane & 15);
      #pragma unroll
      for (int reg = 0; reg < 4; ++reg) {
        int row = rowA0 + wm0 + mf*16 + (lane >> 4)*4 + reg;
        float v = acc[mf][nf][reg];
        if constexpr (EPI == 0) { // QKV scatter
          int wh = col / 768, cc = col % 768;
          int hh = cc >> 6, d = col & 63;
          int b = row >> 9, s = row & 511;
          const float* bias = wh==0 ? p.bq : (wh==1 ? p.bk : p.bv);
          u16 o = f2bf(v + bias[cc]);
          if (wh == 0)      p.qO[((((size_t)b*12 + hh)*512 + s) << 6) + d] = o;
          else if (wh == 1) p.kO[((((size_t)b*12 + hh)*512 + s) << 6) + d] = o;
          else              p.vO[((((size_t)b*12 + hh)*64  + d) << 9) + s] = o;
        } else if constexpr (EPI == 2) { // bf16 partial (summed in ln_fused)
          p.outB[(size_t)bz * p.sOut + (size_t)row * p.N + col] = f2bf(v);
        } else { // gelu -> bf16
          float xg = v + p.bias[col];
          float gg = 0.5f * xg * (1.f + erff(xg * 0.70710678118f));
          p.outB[(size_t)row * p.N + col] = f2bf(gg);
        }
      }
    }
  }
}

// ---------------------------------------------------------------- flash attention v4 (r12 structure: staged+swizzled)
template<int RAT>
__global__ __launch_bounds__(256) void flash_attn(
    const u16* __restrict__ q, const u16* __restrict__ k, const u16* __restrict__ v,
    const int* __restrict__ mask, u16* __restrict__ ctx,
    const float* __restrict__ kr, const int* __restrict__ rel,
    float* __restrict__ wbins) {
  const int head = blockIdx.x;   // 0..47 (48 % 8 == 0 -> same head on one XCD)
  const int bm = blockIdx.y;     // 0..15
  const int b = head / 12, hh = head % 12;
  const int tid = threadIdx.x, wave = tid >> 6, lane = tid & 63;
  const int wr = wave >> 1, wc = wave & 1;
  const int row0 = bm * 32;
  const u16* qb = q + (size_t)head * 512 * 64;
  const u16* kb = k + (size_t)head * 512 * 64;
  const u16* vb = v + (size_t)head * 64 * 512;   // [d][t]

  __shared__ __align__(16) u16 Kl[2][64*64];
  __shared__ __align__(16) u16 Vl[2][64*64];
  __shared__ __align__(16) u16 pw[4][16*72];     // P bounce; aliased: kr bf16, f32 merge buf
  __shared__ float em_lds[512];
  __shared__ float mlb[2][16][2];
  __shared__ float qlds[RAT ? 32 : 1][RAT ? 52 : 1];
  __shared__ float wlds[RAT ? 2 : 1][RAT ? 32 : 1][RAT ? 50 : 1];
  __shared__ float scl[RAT ? 2 : 1][RAT ? 32 : 1];
  __shared__ float aex[RAT ? 32 : 1][RAT ? 3 : 1];

  for (int i = tid; i < 512; i += 256)
    em_lds[i] = -10000.f * (1.f - (float)mask[b*512 + i]);
  u16* Krl = (u16*)pw;
  if constexpr (RAT) {
    for (int i = tid; i < 2*32*50; i += 256) ((float*)wlds)[i] = 0.f;
    for (int i = tid; i < 64*64; i += 256) {
      int r = i >> 6, c = i & 63;
      Krl[i] = (r < 50) ? f2bf(kr[r*64 + c]) : (u16)0;
    }
  }

  const int qrow = row0 + wr*16 + (lane & 15);
  const int g = lane >> 4;
  bf16x8 qf[2];
  qf[0] = ld_bf8(qb + (size_t)qrow*64 +      g*8);
  qf[1] = ld_bf8(qb + (size_t)qrow*64 + 32 + g*8);
  __syncthreads();

  if constexpr (RAT) {
    #pragma unroll
    for (int nf = 0; nf < 2; ++nf) {
      f32x4 a = f32x4{0.f,0.f,0.f,0.f};
      #pragma unroll
      for (int ks = 0; ks < 2; ++ks) {
        bf16x8 krf = ld_bf8(Krl + (wc*32 + nf*16 + (lane&15))*64 + ks*32 + g*8);
        a = mfma16(qf[ks], krf, a);
      }
      int rr = wc*32 + nf*16 + (lane & 15);
      if (rr < 50) {
        #pragma unroll
        for (int reg = 0; reg < 4; ++reg)
          qlds[wr*16 + g*4 + reg][rr] = a[reg];
      }
    }
    __syncthreads();
  }

  f32x4 ctxacc[4];
  #pragma unroll
  for (int nf = 0; nf < 4; ++nf) ctxacc[nf] = f32x4{0.f,0.f,0.f,0.f};
  float mrun[4], lrun[4];
  #pragma unroll
  for (int r = 0; r < 4; ++r) { mrun[r] = -3.0e38f; lrun[r] = 0.f; }

  for (int it = 0; it < 4; ++it) {
    #pragma unroll
    for (int j = 0; j < 2; ++j) {
      int s = j*256 + tid;
      int prow = s >> 3, c16 = (s & 7) ^ (prow & 7);
      int t0a = it*64, t0b = 256 + it*64;
      gload16(kb + (size_t)(t0a + prow)*64 + c16*8, Kl[0] + s*8);
      gload16(kb + (size_t)(t0b + prow)*64 + c16*8, Kl[1] + s*8);
      gload16(vb + (size_t)prow*512 + t0a + c16*8, Vl[0] + s*8);
      gload16(vb + (size_t)prow*512 + t0b + c16*8, Vl[1] + s*8);
    }
    __syncthreads();
    const int tbase = wc*256 + it*64;

    f32x4 s[4];
    #pragma unroll
    for (int nf = 0; nf < 4; ++nf) s[nf] = f32x4{0.f,0.f,0.f,0.f};
    #pragma unroll
    for (int ks = 0; ks < 2; ++ks)
      #pragma unroll
      for (int nf = 0; nf < 4; ++nf) {
        int row = nf*16 + (lane & 15);
        int c16 = (ks*4 + g) ^ (row & 7);
        bf16x8 kf = ld_bf8(Kl[wc] + row*64 + c16*8);
        s[nf] = mfma16(qf[ks], kf, s[nf]);
      }

    u32 rr4[RAT ? 4 : 1];
    if constexpr (RAT) {
      #pragma unroll
      for (int nf = 0; nf < 4; ++nf) {
        int tt = tbase + nf*16 + (lane & 15);
        u32 pack = 0;
        #pragma unroll
        for (int reg = 0; reg < 4; ++reg) {
          int rl = wr*16 + g*4 + reg;
          int rr = rel[((size_t)(b*512 + row0 + rl))*512 + tt];
          pack |= (u32)rr << (8*reg);
          s[nf][reg] += qlds[rl][rr];
        }
        rr4[nf] = pack;
      }
    }

    float em4[4];
    #pragma unroll
    for (int nf = 0; nf < 4; ++nf) em4[nf] = em_lds[tbase + nf*16 + (lane & 15)];

    float scale_[4];
    #pragma unroll
    for (int reg = 0; reg < 4; ++reg) {
      float pm = -3.0e38f;
      #pragma unroll
      for (int nf = 0; nf < 4; ++nf) {
        s[nf][reg] = s[nf][reg]*0.125f + em4[nf];
        pm = fmaxf(pm, s[nf][reg]);
      }
      #pragma unroll
      for (int o = 1; o < 16; o <<= 1) pm = fmaxf(pm, __shfl_xor(pm, o));
      float mnew = fmaxf(mrun[reg], pm);
      float sc = __expf(mrun[reg] - mnew);
      mrun[reg] = mnew;
      scale_[reg] = sc;
      float lsum = 0.f;
      #pragma unroll
      for (int nf = 0; nf < 4; ++nf) {
        float e = __expf(s[nf][reg] - mnew);
        s[nf][reg] = e;
        lsum += e;
      }
      #pragma unroll
      for (int o = 1; o < 16; o <<= 1) lsum += __shfl_xor(lsum, o);
      lrun[reg] = lrun[reg]*sc + lsum;
      if constexpr (RAT) {
        if ((lane & 15) == 0) scl[wc][wr*16 + g*4 + reg] = sc;
      }
    }

    if constexpr (RAT) {
      for (int i = lane; i < 16*50; i += 64) {
        int r = i / 50;
        wlds[wc][wr*16 + r][i % 50] *= scl[wc][wr*16 + r];
      }
      #pragma unroll
      for (int nf = 0; nf < 4; ++nf)
        #pragma unroll
        for (int reg = 0; reg < 4; ++reg) {
          int rl = wr*16 + g*4 + reg;
          int rr = (rr4[nf] >> (8*reg)) & 255;
          atomicAdd(&wlds[wc][rl][rr], s[nf][reg]);
        }
    }

    #pragma unroll
    for (int nf = 0; nf < 4; ++nf)
      #pragma unroll
      for (int reg = 0; reg < 4; ++reg) {
        int qq = g*4 + reg;
        pw[wave][qq*72 + nf*16 + (lane & 15)] = f2bf(s[nf][reg]);
      }

    #pragma unroll
    for (int nf = 0; nf < 4; ++nf)
      #pragma unroll
      for (int reg = 0; reg < 4; ++reg)
        ctxacc[nf][reg] *= scale_[reg];
    #pragma unroll
    for (int ks = 0; ks < 2; ++ks) {
      bf16x8 pf = ld_bf8(pw[wave] + (lane & 15)*72 + ks*32 + g*8);
      #pragma unroll
      for (int nf = 0; nf < 4; ++nf) {
        int row = nf*16 + (lane & 15);
        int c16 = (ks*4 + g) ^ (row & 7);
        bf16x8 vf = ld_bf8(Vl[wc] + row*64 + c16*8);
        ctxacc[nf] = mfma16(pf, vf, ctxacc[nf]);
      }
    }
    __syncthreads();
  }

  // ---- merge the two t-half partials
  float* mergeF = (float*)pw;
  if (wc == 1) {
    #pragma unroll
    for (int nf = 0; nf < 4; ++nf)
      #pragma unroll
      for (int reg = 0; reg < 4; ++reg)
        mergeF[(wr*16 + g*4 + reg)*66 + nf*16 + (lane & 15)] = ctxacc[nf][reg];
    if ((lane & 15) == 0) {
      #pragma unroll
      for (int reg = 0; reg < 4; ++reg) {
        mlb[wr][g*4 + reg][0] = mrun[reg];
        mlb[wr][g*4 + reg][1] = lrun[reg];
      }
    }
  }
  __syncthreads();
  if (wc == 0) {
    float a1[4], a2[4], linv[4];
    #pragma unroll
    for (int reg = 0; reg < 4; ++reg) {
      int r = g*4 + reg;
      float m2 = mlb[wr][r][0], l2 = mlb[wr][r][1];
      float mn = fmaxf(mrun[reg], m2);
      a1[reg] = __expf(mrun[reg] - mn);
      a2[reg] = __expf(m2 - mn);
      linv[reg] = 1.f / (lrun[reg]*a1[reg] + l2*a2[reg]);
      if constexpr (RAT) {
        if ((lane & 15) == 0) {
          aex[wr*16 + r][0] = a1[reg];
          aex[wr*16 + r][1] = a2[reg];
          aex[wr*16 + r][2] = linv[reg];
        }
      }
    }
    #pragma unroll
    for (int nf = 0; nf < 4; ++nf)
      #pragma unroll
      for (int reg = 0; reg < 4; ++reg) {
        int r = wr*16 + g*4 + reg;
        int qg = row0 + r;
        int d = nf*16 + (lane & 15);
        float v2 = mergeF[r*66 + d];
        ctx[((size_t)(b*512 + qg))*768 + hh*64 + d] =
            f2bf((ctxacc[nf][reg]*a1[reg] + v2*a2[reg]) * linv[reg]);
      }
  }
  if constexpr (RAT) {
    __syncthreads();
    for (int i = tid; i < 32*50; i += 256) {
      int sr = i / 50, rr = i % 50;
      wbins[((size_t)head*512 + row0 + sr)*50 + rr] =
          (wlds[0][sr][rr]*aex[sr][0] + wlds[1][sr][rr]*aex[sr][1]) * aex[sr][2];
    }
  }
}

// ---------------------------------------------------------------- RAT apply (layer 6)
__global__ __launch_bounds__(256) void rat_apply(const float* __restrict__ wbins,
    const float* __restrict__ vr, u16* __restrict__ ctx) {
  __shared__ float vrl[50*64];
  __shared__ float wl[32*50];
  int tid = threadIdx.x;
  int rows0 = blockIdx.x * 32;
  for (int i = tid; i < 50*64; i += 256) vrl[i] = vr[i];
  for (int i = tid; i < 32*50; i += 256) wl[i] = wbins[(size_t)rows0*50 + i];
  __syncthreads();
  int wave = tid >> 6, lane = tid & 63;
  #pragma unroll
  for (int i = 0; i < 8; ++i) {
    int r = wave*8 + i;
    size_t idx = (size_t)rows0 + r;
    float acc = 0.f;
    #pragma unroll
    for (int j = 0; j < 50; ++j) acc += wl[r*50 + j] * vrl[j*64 + lane];
    int s = (int)(idx & 511); size_t bh = idx >> 9;
    int b = (int)(bh / 12), hh = (int)(bh % 12);
    u16* cp = ctx + ((size_t)(b*512 + s))*768 + hh*64 + lane;
    *cp = f2bf(bf2f(*cp) + acc);
  }
}

// ---------------------------------------------------------------- embeddings + LN
__global__ __launch_bounds__(256) void embed_ln(const int* __restrict__ ids,
    const float* __restrict__ we, const float* __restrict__ pe, const float* __restrict__ te,
    const float* __restrict__ g, const float* __restrict__ b,
    float* __restrict__ hF, u16* __restrict__ hB) {
  int row = blockIdx.x, tid = threadIdx.x;
  int s = row & 511;
  int id = ids[row];
  float x[3];
  #pragma unroll
  for (int j = 0; j < 3; ++j) {
    int d = tid + j*256;
    x[j] = we[(size_t)id*768 + d] + pe[(size_t)s*768 + d] + te[d];
  }
  __shared__ float red[4];
  float sm = x[0] + x[1] + x[2];
  #pragma unroll
  for (int o = 32; o; o >>= 1) sm += __shfl_xor(sm, o);
  if (!(tid & 63)) red[tid >> 6] = sm;
  __syncthreads();
  float mean = (red[0]+red[1]+red[2]+red[3]) * (1.f/768.f);
  __syncthreads();
  float q = 0.f;
  #pragma unroll
  for (int j = 0; j < 3; ++j) { float d = x[j] - mean; q += d*d; }
  #pragma unroll
  for (int o = 32; o; o >>= 1) q += __shfl_xor(q, o);
  if (!(tid & 63)) red[tid >> 6] = q;
  __syncthreads();
  float inv = rsqrtf((red[0]+red[1]+red[2]+red[3]) * (1.f/768.f) + 1e-12f);
  #pragma unroll
  for (int j = 0; j < 3; ++j) {
    int d = tid + j*256;
    float y = (x[j] - mean) * inv * g[d] + b[d];
    hF[(size_t)row*768 + d] = y;
    hB[(size_t)row*768 + d] = f2bf(y);
  }
}

// LN over bf16 partials (p0[+p1][+p2][+p3]) + bias + res(f32)
__global__ __launch_bounds__(256) void ln_fused(const u16* __restrict__ p0,
    const u16* __restrict__ p1, const u16* __restrict__ p2, const u16* __restrict__ p3,
    int np, const float* __restrict__ bias, const float* __restrict__ res,
    const float* __restrict__ g, const float* __restrict__ b,
    float* __restrict__ oF, u16* __restrict__ oB) {
  int row = blockIdx.x, tid = threadIdx.x;
  size_t base = (size_t)row * 768;
  float v[3];
  #pragma unroll
  for (int j = 0; j < 3; ++j) {
    int d = tid + j*256;
    float x = bf2f(p0[base + d]);
    if (np > 1) x += bf2f(p1[base + d]);
    if (np > 2) x += bf2f(p2[base + d]);
    if (np > 3) x += bf2f(p3[base + d]);
    v[j] = x + bias[d] + res[base + d];
  }
  __shared__ float red[4];
  float sm = v[0] + v[1] + v[2];
  #pragma unroll
  for (int o = 32; o; o >>= 1) sm += __shfl_xor(sm, o);
  if (!(tid & 63)) red[tid >> 6] = sm;
  __syncthreads();
  float mean = (red[0]+red[1]+red[2]+red[3]) * (1.f/768.f);
  __syncthreads();
  float q = 0.f;
  #pragma unroll
  for (int j = 0; j < 3; ++j) { float d = v[j] - mean; q += d*d; }
  #pragma unroll
  for (int o = 32; o; o >>= 1) q += __shfl_xor(q, o);
  if (!(tid & 63)) red[tid >> 6] = q;
  __syncthreads();
  float inv = rsqrtf((red[0]+red[1]+red[2]+red[3]) * (1.f/768.f) + 1e-12f);
  #pragma unroll
  for (int j = 0; j < 3; ++j) {
    int d = tid + j*256;
    float y = (v[j] - mean) * inv * g[d] + b[d];
    oF[base + d] = y;
    oB[base + d] = f2bf(y);
  }
}

// ---------------------------------------------------------------- tail
__global__ __launch_bounds__(256) void pooler_k(const float* __restrict__ h,
    const float* __restrict__ w, const float* __restrict__ bias, float* __restrict__ out) {
  int b = blockIdx.x, tid = threadIdx.x;
  __shared__ float hr[768];
  for (int i = tid; i < 768; i += 256) hr[i] = h[((size_t)b*512)*768 + i];
  __syncthreads();
  float a0 = 0.f, a1 = 0.f, a2 = 0.f;
  for (int kk = 0; kk < 768; ++kk) {
    float hv = hr[kk];
    const float* wr = w + (size_t)kk*768;
    a0 += hv * wr[tid]; a1 += hv * wr[tid+256]; a2 += hv * wr[tid+512];
  }
  out[(size_t)b*768 + tid]       = tanhf(a0 + bias[tid]);
  out[(size_t)b*768 + tid + 256] = tanhf(a1 + bias[tid+256]);
  out[(size_t)b*768 + tid + 512] = tanhf(a2 + bias[tid+512]);
}

// ---------------------------------------------------------------- host
extern "C" void kernel_launch(void* const* d_in, const int* in_sizes, int n_in,
                              void* d_out, int out_size, void* d_ws, size_t ws_size,
                              hipStream_t stream) {
  const int*   ids   = (const int*)d_in[0];
  const int*   rel   = (const int*)d_in[1];
  const int*   amask = (const int*)d_in[2];
  const float* we    = (const float*)d_in[3];
  const float* pe    = (const float*)d_in[4];
  const float* te    = (const float*)d_in[5];
  const float* eg    = (const float*)d_in[6];
  const float* ebb   = (const float*)d_in[7];
  const float* Wq    = (const float*)d_in[8];
  const float* bq    = (const float*)d_in[9];
  const float* Wk    = (const float*)d_in[10];
  const float* bk    = (const float*)d_in[11];
  const float* Wv    = (const float*)d_in[12];
  const float* bv    = (const float*)d_in[13];
  const float* Wo    = (const float*)d_in[14];
  const float* bo    = (const float*)d_in[15];
  const float* g1    = (const float*)d_in[16];
  const float* b1    = (const float*)d_in[17];
  const float* Wi    = (const float*)d_in[18];
  const float* bi    = (const float*)d_in[19];
  const float* Wf    = (const float*)d_in[20];
  const float* bfp   = (const float*)d_in[21];
  const float* g2    = (const float*)d_in[22];
  const float* b2    = (const float*)d_in[23];
  const float* krel  = (const float*)d_in[24];
  const float* vrel  = (const float*)d_in[25];
  const float* pwp   = (const float*)d_in[26];
  const float* pbp   = (const float*)d_in[27];
  (void)in_sizes; (void)n_in; (void)out_size;

  char* ws = (char*)d_ws;
  size_t off = 0;
  auto take = [&](size_t bytes) { char* p = ws + off; off += (bytes + 255) & ~(size_t)255; return p; };
  float* hF   = (float*)take((size_t)2048*768*4);
  u16*   hB   = (u16*)take((size_t)2048*768*2);
  float* atF  = (float*)take((size_t)2048*768*4);
  u16*   atB  = (u16*)take((size_t)2048*768*2);
  u16*   qB   = (u16*)take((size_t)2048*768*2);
  u16*   kB   = (u16*)take((size_t)2048*768*2);
  u16*   vB   = (u16*)take((size_t)2048*768*2);
  u16*   ctxB = (u16*)take((size_t)2048*768*2);
  u16*   tmpB = (u16*)take((size_t)4*2048*768*2);     // 4 bf16 split-K partial planes
  u16*   ffB  = (u16*)take((size_t)2048*3072*2);
  float* wbF  = (float*)take((size_t)24576*50*4);
  const size_t PSTRIDE = (size_t)2048*768;

  // weight buffers: pre-convert all 12 layers in one launch if workspace allows
  const size_t WQKV = (size_t)2304*768, WWO = (size_t)768*768;
  const size_t WWI = (size_t)768*3072, WWF = (size_t)3072*768;
  const size_t wLayerBytes = (WQKV + WWO + WWI + WWF) * 2;
  const bool preall = (off + 12*wLayerBytes + 65536 <= ws_size);
  const int NL = preall ? 12 : 1;
  u16* wqkvB = (u16*)take(WQKV*2*NL);
  u16* woB   = (u16*)take(WWO*2*NL);
  u16* wiB   = (u16*)take(WWI*2*NL);
  u16* wfB   = (u16*)take(WWF*2*NL);

  ConvP cp{Wq, Wk, Wv, Wo, Wi, Wf, wqkvB, woB, wiB, wfB,
           preall ? (long)WQKV : 0, preall ? (long)WWO : 0,
           preall ? (long)WWI : 0, preall ? (long)WWF : 0};

  embed_ln<<<2048, 256, 0, stream>>>(ids, we, pe, te, eg, ebb, hF, hB);
  if (preall) conv_weights<<<12*1728, 256, 0, stream>>>(cp, 0);

  for (int l = 0; l < 12; ++l) {
    if (!preall) conv_weights<<<1728, 256, 0, stream>>>(cp, l);
    const u16* wqkv_l = wqkvB + (size_t)l*cp.doqkv;
    const u16* wo_l   = woB   + (size_t)l*cp.doo;
    const u16* wi_l   = wiB   + (size_t)l*cp.doi;
    const u16* wf_l   = wfB   + (size_t)l*cp.dof;

    GP pq{}; pq.A = hB; pq.B = wqkv_l; pq.K = 768; pq.N = 2304;
    pq.bq = bq + l*768; pq.bk = bk + l*768; pq.bv = bv + l*768;
    pq.qO = qB; pq.kO = kB; pq.vO = vB;
    gemm_bt<64,128,4,0,1><<<dim3(18,32,1), 256, 0, stream>>>(pq);

    if (l == 6) {
      flash_attn<1><<<dim3(48,16), 256, 0, stream>>>(qB, kB, vB, amask, ctxB,
                                                     krel + 6*50*64, rel, wbF);
      rat_apply<<<768, 256, 0, stream>>>(wbF, vrel + 6*50*64, ctxB);
    } else {
      flash_attn<0><<<dim3(48,16), 256, 0, stream>>>(qB, kB, vB, amask, ctxB,
                                                     nullptr, nullptr, nullptr);
    }

    GP po{}; po.A = ctxB; po.B = wo_l; po.K = 768; po.N = 768; po.sOut = PSTRIDE;
    po.outB = tmpB;
    gemm_bt<64,128,4,2,2><<<dim3(6,32,2), 256, 0, stream>>>(po);
    ln_fused<<<2048, 256, 0, stream>>>(tmpB, tmpB + PSTRIDE, nullptr, nullptr, 2,
                                       bo + l*768, hF, g1 + l*768, b1 + l*768, atF, atB);

    GP pf1{}; pf1.A = atB; pf1.B = wi_l; pf1.K = 768; pf1.N = 3072;
    pf1.bias = bi + (size_t)l*3072; pf1.outB = ffB;
    gemm_bt<64,128,4,3,1><<<dim3(24,32,1), 256, 0, stream>>>(pf1);

    GP pf2{}; pf2.A = ffB; pf2.B = wf_l; pf2.K = 3072; pf2.N = 768; pf2.sOut = PSTRIDE;
    pf2.outB = tmpB;
    gemm_bt<64,128,4,2,4><<<dim3(6,32,4), 256, 0, stream>>>(pf2);
    // final layer: write normalized h directly into d_out (skip copy kernel)
    float* houtF = (l == 11) ? (float*)d_out : hF;
    ln_fused<<<2048, 256, 0, stream>>>(tmpB, tmpB + PSTRIDE, tmpB + 2*PSTRIDE, tmpB + 3*PSTRIDE, 4,
                                       bfp + l*768, atF, g2 + l*768, b2 + l*768, houtF, hB);
  }

  pooler_k<<<4, 256, 0, stream>>>((const float*)d_out, pwp, pbp, (float*)d_out + (size_t)2048*768);
}

// Round 16
// 1611.529 us; speedup vs baseline: 1.0915x; 1.0121x over previous
//
#include <hip/hip_runtime.h>
#include <math.h>

typedef unsigned short u16;
typedef unsigned int   u32;
typedef __bf16  bf16x8 __attribute__((ext_vector_type(8)));
typedef float   f32x4  __attribute__((ext_vector_type(4)));
typedef u16     u16x8  __attribute__((ext_vector_type(8)));
typedef u16     u16x4  __attribute__((ext_vector_type(4)));

__device__ __forceinline__ u16 f2bf(float f) {
  u32 u = __builtin_bit_cast(u32, f);
  u32 r = (u + 0x7fffu + ((u >> 16) & 1u)) >> 16;
  return (u16)r;
}
__device__ __forceinline__ float bf2f(u16 h) {
  u32 u = ((u32)h) << 16;
  return __builtin_bit_cast(float, u);
}
__device__ __forceinline__ void gload16(const void* g, void* l) {
  __builtin_amdgcn_global_load_lds((const __attribute__((address_space(1))) void*)g,
                                   (__attribute__((address_space(3))) void*)l, 16, 0, 0);
}
__device__ __forceinline__ bf16x8 ld_bf8(const u16* p) {
  u16x8 v = *(const u16x8*)p;
  return __builtin_bit_cast(bf16x8, v);
}
__device__ __forceinline__ f32x4 mfma16(bf16x8 a, bf16x8 b, f32x4 c) {
  return __builtin_amdgcn_mfma_f32_16x16x32_bf16(a, b, c, 0, 0, 0);
}

// ---------------------------------------------------------------- weights
struct ConvP {
  const float *wq, *wk, *wv, *wo, *wi, *wf;   // layer-0 bases
  u16 *oqkv, *oo, *oi, *of;                   // dst bases
  long doqkv, doo, doi, dof;                  // dst layer strides (elements)
};
// transpose+convert f32 [K,N] -> bf16 [N,K]; 64x64 tiles, 1728 tiles/layer.
__global__ __launch_bounds__(256) void conv_weights(ConvP p, int l0) {
  int l = l0 + blockIdx.x / 1728;
  int t = blockIdx.x % 1728;
  const float* in; u16* out; int K, N, tn, tk;
  if (t < 432) { int wh = t / 144, tt = t % 144;
    in = (wh==0 ? p.wq : (wh==1 ? p.wk : p.wv)) + (size_t)l*768*768;
    out = p.oqkv + (size_t)l*p.doqkv + (size_t)wh * 768 * 768;
    K = 768; N = 768; tn = tt % 12; tk = tt / 12;
  } else if (t < 576) { int tt = t - 432;
    in = p.wo + (size_t)l*768*768; out = p.oo + (size_t)l*p.doo;
    K=768;  N=768;  tn=tt%12; tk=tt/12;
  } else if (t < 1152) { int tt = t - 576;
    in = p.wi + (size_t)l*768*3072; out = p.oi + (size_t)l*p.doi;
    K=768;  N=3072; tn=tt%48; tk=tt/48;
  } else { int tt = t - 1152;
    in = p.wf + (size_t)l*768*3072; out = p.of + (size_t)l*p.dof;
    K=3072; N=768;  tn=tt%12; tk=tt/12;
  }
  int n0 = tn*64, k0 = tk*64;
  __shared__ float tile[64][65];
  int tid = threadIdx.x;
  int tx = tid & 15, ry = tid >> 4;
  #pragma unroll
  for (int j = 0; j < 4; ++j) {
    int kk = j*16 + ry;
    float4 rv = *(const float4*)(in + (size_t)(k0 + kk) * N + n0 + tx*4);
    tile[kk][tx*4+0] = rv.x; tile[kk][tx*4+1] = rv.y;
    tile[kk][tx*4+2] = rv.z; tile[kk][tx*4+3] = rv.w;
  }
  __syncthreads();
  int tx2 = tid & 7, ry2 = tid >> 3;
  #pragma unroll
  for (int j = 0; j < 2; ++j) {
    int nn = j*32 + ry2;
    u16x8 ov;
    #pragma unroll
    for (int c = 0; c < 8; ++c) ov[c] = f2bf(tile[tx2*8+c][nn]);
    *(u16x8*)(out + (size_t)(n0 + nn) * K + k0 + tx2*8) = ov;
  }
}

// ---------------------------------------------------------------- GEMM (A[M,K] bf16 x B^T[N,K] bf16)
struct GP {
  const u16* A; const u16* B;
  int K, N;
  long sA, sB, sOut;
  const float* bias; const float* res;
  float* outF; u16* outB;
  const float* bq; const float* bk; const float* bv;
  u16* qO; u16* kO; u16* vO;
};

// EPI: 0=QKV scatter, 2=bf16 partial, 3=gelu->bf16
template<int BM, int BN, int WAVES, int EPI, int KS>
__global__ __launch_bounds__(WAVES*64) void gemm_bt(GP p) {
  constexpr int THREADS = WAVES * 64;
  constexpr int WC = WAVES / 2;
  constexpr int WM = BM / 2, WN = BN / WC, MR = WM / 16, NR = WN / 16;
  constexpr int AIT = BM * 64 / (THREADS * 8);
  constexpr int BIT = BN * 64 / (THREADS * 8);
  const int tid = threadIdx.x;
  const int wave = tid >> 6, lane = tid & 63;
  const int wr = wave / WC, wc = wave % WC;
  const int wm0 = wr * WM, wn0 = wc * WN;
  const int bn = blockIdx.x, bm = blockIdx.y, bz = blockIdx.z;
  const int K = p.K;
  const int kLen = K / KS;
  const int kBeg = (KS > 1) ? bz * kLen : 0;
  const u16* A  = p.A + ((KS > 1) ? 0 : (size_t)bz * p.sA);
  const u16* Bp = p.B + ((KS > 1) ? 0 : (size_t)bz * p.sB);
  const int rowA0 = bm * BM, colB0 = bn * BN;

  __shared__ __align__(16) u16 lds[(BM + BN) * 64];
  u16* Al = lds; u16* Bl = lds + BM * 64;

  f32x4 acc[MR][NR];
  #pragma unroll
  for (int i = 0; i < MR; ++i)
    #pragma unroll
    for (int j = 0; j < NR; ++j) acc[i][j] = f32x4{0.f,0.f,0.f,0.f};

  for (int kt = kBeg; kt < kBeg + kLen; kt += 64) {
    #pragma unroll
    for (int it = 0; it < AIT; ++it) {
      int e = tid * 8 + it * THREADS * 8;
      gload16(A + (size_t)(rowA0 + (e >> 6)) * K + kt + (e & 63), Al + e);
    }
    #pragma unroll
    for (int it = 0; it < BIT; ++it) {
      int e = tid * 8 + it * THREADS * 8;
      gload16(Bp + (size_t)(colB0 + (e >> 6)) * K + kt + (e & 63), Bl + e);
    }
    __syncthreads();
    #pragma unroll
    for (int ks = 0; ks < 2; ++ks) {
      bf16x8 av[MR]; bf16x8 bw[NR];
      #pragma unroll
      for (int mf = 0; mf < MR; ++mf)
        av[mf] = ld_bf8(Al + (wm0 + mf*16 + (lane&15))*64 + ks*32 + (lane>>4)*8);
      #pragma unroll
      for (int nf = 0; nf < NR; ++nf)
        bw[nf] = ld_bf8(Bl + (wn0 + nf*16 + (lane&15))*64 + ks*32 + (lane>>4)*8);
      #pragma unroll
      for (int mf = 0; mf < MR; ++mf)
        #pragma unroll
        for (int nf = 0; nf < NR; ++nf)
          acc[mf][nf] = mfma16(av[mf], bw[nf], acc[mf][nf]);
    }
    __syncthreads();
  }

  #pragma unroll
  for (int mf = 0; mf < MR; ++mf) {
    #pragma unroll
    for (int nf = 0; nf < NR; ++nf) {
      int col = colB0 + wn0 + nf*16 + (lane & 15);
      #pragma unroll
      for (int reg = 0; reg < 4; ++reg) {
        int row = rowA0 + wm0 + mf*16 + (lane >> 4)*4 + reg;
        float v = acc[mf][nf][reg];
        if constexpr (EPI == 0) { // QKV scatter
          int wh = col / 768, cc = col % 768;
          int hh = cc >> 6, d = col & 63;
          int b = row >> 9, s = row & 511;
          const float* bias = wh==0 ? p.bq : (wh==1 ? p.bk : p.bv);
          u16 o = f2bf(v + bias[cc]);
          if (wh == 0)      p.qO[((((size_t)b*12 + hh)*512 + s) << 6) + d] = o;
          else if (wh == 1) p.kO[((((size_t)b*12 + hh)*512 + s) << 6) + d] = o;
          else              p.vO[((((size_t)b*12 + hh)*64  + d) << 9) + s] = o;
        } else if constexpr (EPI == 2) { // bf16 partial (summed in ln_fused)
          p.outB[(size_t)bz * p.sOut + (size_t)row * p.N + col] = f2bf(v);
        } else { // gelu -> bf16
          float xg = v + p.bias[col];
          float gg = 0.5f * xg * (1.f + erff(xg * 0.70710678118f));
          p.outB[(size_t)row * p.N + col] = f2bf(gg);
        }
      }
    }
  }
}

// ---------------------------------------------------------------- flash attention v4 (staged+swizzled)
template<int RAT>
__global__ __launch_bounds__(256) void flash_attn(
    const u16* __restrict__ q, const u16* __restrict__ k, const u16* __restrict__ v,
    const int* __restrict__ mask, u16* __restrict__ ctx,
    const float* __restrict__ kr, const int* __restrict__ rel,
    float* __restrict__ wbins) {
  const int head = blockIdx.x;   // 0..47 (48 % 8 == 0 -> same head on one XCD)
  const int bm = blockIdx.y;     // 0..15
  const int b = head / 12, hh = head % 12;
  const int tid = threadIdx.x, wave = tid >> 6, lane = tid & 63;
  const int wr = wave >> 1, wc = wave & 1;
  const int row0 = bm * 32;
  const u16* qb = q + (size_t)head * 512 * 64;
  const u16* kb = k + (size_t)head * 512 * 64;
  const u16* vb = v + (size_t)head * 64 * 512;   // [d][t]

  __shared__ __align__(16) u16 Kl[2][64*64];
  __shared__ __align__(16) u16 Vl[2][64*64];
  __shared__ __align__(16) u16 pw[4][16*72];     // P bounce; aliased: kr bf16, f32 merge buf
  __shared__ float em_lds[512];
  __shared__ float mlb[2][16][2];
  __shared__ float qlds[RAT ? 32 : 1][RAT ? 52 : 1];
  __shared__ float wlds[RAT ? 2 : 1][RAT ? 32 : 1][RAT ? 50 : 1];
  __shared__ float scl[RAT ? 2 : 1][RAT ? 32 : 1];
  __shared__ float aex[RAT ? 32 : 1][RAT ? 3 : 1];

  for (int i = tid; i < 512; i += 256)
    em_lds[i] = -10000.f * (1.f - (float)mask[b*512 + i]);
  u16* Krl = (u16*)pw;
  if constexpr (RAT) {
    for (int i = tid; i < 2*32*50; i += 256) ((float*)wlds)[i] = 0.f;
    for (int i = tid; i < 64*64; i += 256) {
      int r = i >> 6, c = i & 63;
      Krl[i] = (r < 50) ? f2bf(kr[r*64 + c]) : (u16)0;
    }
  }

  const int qrow = row0 + wr*16 + (lane & 15);
  const int g = lane >> 4;
  bf16x8 qf[2];
  qf[0] = ld_bf8(qb + (size_t)qrow*64 +      g*8);
  qf[1] = ld_bf8(qb + (size_t)qrow*64 + 32 + g*8);
  __syncthreads();

  if constexpr (RAT) {
    #pragma unroll
    for (int nf = 0; nf < 2; ++nf) {
      f32x4 a = f32x4{0.f,0.f,0.f,0.f};
      #pragma unroll
      for (int ks = 0; ks < 2; ++ks) {
        bf16x8 krf = ld_bf8(Krl + (wc*32 + nf*16 + (lane&15))*64 + ks*32 + g*8);
        a = mfma16(qf[ks], krf, a);
      }
      int rr = wc*32 + nf*16 + (lane & 15);
      if (rr < 50) {
        #pragma unroll
        for (int reg = 0; reg < 4; ++reg)
          qlds[wr*16 + g*4 + reg][rr] = a[reg];
      }
    }
    __syncthreads();
  }

  f32x4 ctxacc[4];
  #pragma unroll
  for (int nf = 0; nf < 4; ++nf) ctxacc[nf] = f32x4{0.f,0.f,0.f,0.f};
  float mrun[4], lrun[4];
  #pragma unroll
  for (int r = 0; r < 4; ++r) { mrun[r] = -3.0e38f; lrun[r] = 0.f; }

  for (int it = 0; it < 4; ++it) {
    #pragma unroll
    for (int j = 0; j < 2; ++j) {
      int s = j*256 + tid;
      int prow = s >> 3, c16 = (s & 7) ^ (prow & 7);
      int t0a = it*64, t0b = 256 + it*64;
      gload16(kb + (size_t)(t0a + prow)*64 + c16*8, Kl[0] + s*8);
      gload16(kb + (size_t)(t0b + prow)*64 + c16*8, Kl[1] + s*8);
      gload16(vb + (size_t)prow*512 + t0a + c16*8, Vl[0] + s*8);
      gload16(vb + (size_t)prow*512 + t0b + c16*8, Vl[1] + s*8);
    }
    __syncthreads();
    const int tbase = wc*256 + it*64;

    f32x4 s[4];
    #pragma unroll
    for (int nf = 0; nf < 4; ++nf) s[nf] = f32x4{0.f,0.f,0.f,0.f};
    #pragma unroll
    for (int ks = 0; ks < 2; ++ks)
      #pragma unroll
      for (int nf = 0; nf < 4; ++nf) {
        int row = nf*16 + (lane & 15);
        int c16 = (ks*4 + g) ^ (row & 7);
        bf16x8 kf = ld_bf8(Kl[wc] + row*64 + c16*8);
        s[nf] = mfma16(qf[ks], kf, s[nf]);
      }

    u32 rr4[RAT ? 4 : 1];
    if constexpr (RAT) {
      #pragma unroll
      for (int nf = 0; nf < 4; ++nf) {
        int tt = tbase + nf*16 + (lane & 15);
        u32 pack = 0;
        #pragma unroll
        for (int reg = 0; reg < 4; ++reg) {
          int rl = wr*16 + g*4 + reg;
          int rr = rel[((size_t)(b*512 + row0 + rl))*512 + tt];
          pack |= (u32)rr << (8*reg);
          s[nf][reg] += qlds[rl][rr];
        }
        rr4[nf] = pack;
      }
    }

    float em4[4];
    #pragma unroll
    for (int nf = 0; nf < 4; ++nf) em4[nf] = em_lds[tbase + nf*16 + (lane & 15)];

    float scale_[4];
    #pragma unroll
    for (int reg = 0; reg < 4; ++reg) {
      float pm = -3.0e38f;
      #pragma unroll
      for (int nf = 0; nf < 4; ++nf) {
        s[nf][reg] = s[nf][reg]*0.125f + em4[nf];
        pm = fmaxf(pm, s[nf][reg]);
      }
      #pragma unroll
      for (int o = 1; o < 16; o <<= 1) pm = fmaxf(pm, __shfl_xor(pm, o));
      float mnew = fmaxf(mrun[reg], pm);
      float sc = __expf(mrun[reg] - mnew);
      mrun[reg] = mnew;
      scale_[reg] = sc;
      float lsum = 0.f;
      #pragma unroll
      for (int nf = 0; nf < 4; ++nf) {
        float e = __expf(s[nf][reg] - mnew);
        s[nf][reg] = e;
        lsum += e;
      }
      #pragma unroll
      for (int o = 1; o < 16; o <<= 1) lsum += __shfl_xor(lsum, o);
      lrun[reg] = lrun[reg]*sc + lsum;
      if constexpr (RAT) {
        if ((lane & 15) == 0) scl[wc][wr*16 + g*4 + reg] = sc;
      }
    }

    if constexpr (RAT) {
      for (int i = lane; i < 16*50; i += 64) {
        int r = i / 50;
        wlds[wc][wr*16 + r][i % 50] *= scl[wc][wr*16 + r];
      }
      #pragma unroll
      for (int nf = 0; nf < 4; ++nf)
        #pragma unroll
        for (int reg = 0; reg < 4; ++reg) {
          int rl = wr*16 + g*4 + reg;
          int rr = (rr4[nf] >> (8*reg)) & 255;
          atomicAdd(&wlds[wc][rl][rr], s[nf][reg]);
        }
    }

    #pragma unroll
    for (int nf = 0; nf < 4; ++nf)
      #pragma unroll
      for (int reg = 0; reg < 4; ++reg) {
        int qq = g*4 + reg;
        pw[wave][qq*72 + nf*16 + (lane & 15)] = f2bf(s[nf][reg]);
      }

    #pragma unroll
    for (int nf = 0; nf < 4; ++nf)
      #pragma unroll
      for (int reg = 0; reg < 4; ++reg)
        ctxacc[nf][reg] *= scale_[reg];
    #pragma unroll
    for (int ks = 0; ks < 2; ++ks) {
      bf16x8 pf = ld_bf8(pw[wave] + (lane & 15)*72 + ks*32 + g*8);
      #pragma unroll
      for (int nf = 0; nf < 4; ++nf) {
        int row = nf*16 + (lane & 15);
        int c16 = (ks*4 + g) ^ (row & 7);
        bf16x8 vf = ld_bf8(Vl[wc] + row*64 + c16*8);
        ctxacc[nf] = mfma16(pf, vf, ctxacc[nf]);
      }
    }
    __syncthreads();
  }

  // ---- merge the two t-half partials
  float* mergeF = (float*)pw;
  if (wc == 1) {
    #pragma unroll
    for (int nf = 0; nf < 4; ++nf)
      #pragma unroll
      for (int reg = 0; reg < 4; ++reg)
        mergeF[(wr*16 + g*4 + reg)*66 + nf*16 + (lane & 15)] = ctxacc[nf][reg];
    if ((lane & 15) == 0) {
      #pragma unroll
      for (int reg = 0; reg < 4; ++reg) {
        mlb[wr][g*4 + reg][0] = mrun[reg];
        mlb[wr][g*4 + reg][1] = lrun[reg];
      }
    }
  }
  __syncthreads();
  if (wc == 0) {
    float a1[4], a2[4], linv[4];
    #pragma unroll
    for (int reg = 0; reg < 4; ++reg) {
      int r = g*4 + reg;
      float m2 = mlb[wr][r][0], l2 = mlb[wr][r][1];
      float mn = fmaxf(mrun[reg], m2);
      a1[reg] = __expf(mrun[reg] - mn);
      a2[reg] = __expf(m2 - mn);
      linv[reg] = 1.f / (lrun[reg]*a1[reg] + l2*a2[reg]);
      if constexpr (RAT) {
        if ((lane & 15) == 0) {
          aex[wr*16 + r][0] = a1[reg];
          aex[wr*16 + r][1] = a2[reg];
          aex[wr*16 + r][2] = linv[reg];
        }
      }
    }
    #pragma unroll
    for (int nf = 0; nf < 4; ++nf)
      #pragma unroll
      for (int reg = 0; reg < 4; ++reg) {
        int r = wr*16 + g*4 + reg;
        int qg = row0 + r;
        int d = nf*16 + (lane & 15);
        float v2 = mergeF[r*66 + d];
        ctx[((size_t)(b*512 + qg))*768 + hh*64 + d] =
            f2bf((ctxacc[nf][reg]*a1[reg] + v2*a2[reg]) * linv[reg]);
      }
  }
  if constexpr (RAT) {
    __syncthreads();
    for (int i = tid; i < 32*50; i += 256) {
      int sr = i / 50, rr = i % 50;
      wbins[((size_t)head*512 + row0 + sr)*50 + rr] =
          (wlds[0][sr][rr]*aex[sr][0] + wlds[1][sr][rr]*aex[sr][1]) * aex[sr][2];
    }
  }
}

// ---------------------------------------------------------------- RAT apply (layer 6)
__global__ __launch_bounds__(256) void rat_apply(const float* __restrict__ wbins,
    const float* __restrict__ vr, u16* __restrict__ ctx) {
  __shared__ float vrl[50*64];
  __shared__ float wl[32*50];
  int tid = threadIdx.x;
  int rows0 = blockIdx.x * 32;
  for (int i = tid; i < 50*64; i += 256) vrl[i] = vr[i];
  for (int i = tid; i < 32*50; i += 256) wl[i] = wbins[(size_t)rows0*50 + i];
  __syncthreads();
  int wave = tid >> 6, lane = tid & 63;
  #pragma unroll
  for (int i = 0; i < 8; ++i) {
    int r = wave*8 + i;
    size_t idx = (size_t)rows0 + r;
    float acc = 0.f;
    #pragma unroll
    for (int j = 0; j < 50; ++j) acc += wl[r*50 + j] * vrl[j*64 + lane];
    int s = (int)(idx & 511); size_t bh = idx >> 9;
    int b = (int)(bh / 12), hh = (int)(bh % 12);
    u16* cp = ctx + ((size_t)(b*512 + s))*768 + hh*64 + lane;
    *cp = f2bf(bf2f(*cp) + acc);
  }
}

// ---------------------------------------------------------------- embeddings + LN (bf16 out only)
__global__ __launch_bounds__(256) void embed_ln(const int* __restrict__ ids,
    const float* __restrict__ we, const float* __restrict__ pe, const float* __restrict__ te,
    const float* __restrict__ g, const float* __restrict__ b,
    u16* __restrict__ hB) {
  int row = blockIdx.x, tid = threadIdx.x;
  int s = row & 511;
  int id = ids[row];
  float x[3];
  #pragma unroll
  for (int j = 0; j < 3; ++j) {
    int d = tid + j*256;
    x[j] = we[(size_t)id*768 + d] + pe[(size_t)s*768 + d] + te[d];
  }
  __shared__ float red[4];
  float sm = x[0] + x[1] + x[2];
  #pragma unroll
  for (int o = 32; o; o >>= 1) sm += __shfl_xor(sm, o);
  if (!(tid & 63)) red[tid >> 6] = sm;
  __syncthreads();
  float mean = (red[0]+red[1]+red[2]+red[3]) * (1.f/768.f);
  __syncthreads();
  float q = 0.f;
  #pragma unroll
  for (int j = 0; j < 3; ++j) { float d = x[j] - mean; q += d*d; }
  #pragma unroll
  for (int o = 32; o; o >>= 1) q += __shfl_xor(q, o);
  if (!(tid & 63)) red[tid >> 6] = q;
  __syncthreads();
  float inv = rsqrtf((red[0]+red[1]+red[2]+red[3]) * (1.f/768.f) + 1e-12f);
  #pragma unroll
  for (int j = 0; j < 3; ++j) {
    int d = tid + j*256;
    float y = (x[j] - mean) * inv * g[d] + b[d];
    hB[(size_t)row*768 + d] = f2bf(y);
  }
}

// LN over bf16 partials (p0[+p1][+p2][+p3]) + bias + res(bf16); oF nullable (final layer)
__global__ __launch_bounds__(256) void ln_fused(const u16* __restrict__ p0,
    const u16* __restrict__ p1, const u16* __restrict__ p2, const u16* __restrict__ p3,
    int np, const float* __restrict__ bias, const u16* __restrict__ res,
    const float* __restrict__ g, const float* __restrict__ b,
    float* __restrict__ oF, u16* __restrict__ oB) {
  int row = blockIdx.x, tid = threadIdx.x;
  size_t base = (size_t)row * 768;
  float v[3];
  #pragma unroll
  for (int j = 0; j < 3; ++j) {
    int d = tid + j*256;
    float x = bf2f(p0[base + d]);
    if (np > 1) x += bf2f(p1[base + d]);
    if (np > 2) x += bf2f(p2[base + d]);
    if (np > 3) x += bf2f(p3[base + d]);
    v[j] = x + bias[d] + bf2f(res[base + d]);
  }
  __shared__ float red[4];
  float sm = v[0] + v[1] + v[2];
  #pragma unroll
  for (int o = 32; o; o >>= 1) sm += __shfl_xor(sm, o);
  if (!(tid & 63)) red[tid >> 6] = sm;
  __syncthreads();
  float mean = (red[0]+red[1]+red[2]+red[3]) * (1.f/768.f);
  __syncthreads();
  float q = 0.f;
  #pragma unroll
  for (int j = 0; j < 3; ++j) { float d = v[j] - mean; q += d*d; }
  #pragma unroll
  for (int o = 32; o; o >>= 1) q += __shfl_xor(q, o);
  if (!(tid & 63)) red[tid >> 6] = q;
  __syncthreads();
  float inv = rsqrtf((red[0]+red[1]+red[2]+red[3]) * (1.f/768.f) + 1e-12f);
  #pragma unroll
  for (int j = 0; j < 3; ++j) {
    int d = tid + j*256;
    float y = (v[j] - mean) * inv * g[d] + b[d];
    if (oF) oF[base + d] = y;
    oB[base + d] = f2bf(y);
  }
}

// ---------------------------------------------------------------- tail
__global__ __launch_bounds__(256) void pooler_k(const float* __restrict__ h,
    const float* __restrict__ w, const float* __restrict__ bias, float* __restrict__ out) {
  int b = blockIdx.x, tid = threadIdx.x;
  __shared__ float hr[768];
  for (int i = tid; i < 768; i += 256) hr[i] = h[((size_t)b*512)*768 + i];
  __syncthreads();
  float a0 = 0.f, a1 = 0.f, a2 = 0.f;
  for (int kk = 0; kk < 768; ++kk) {
    float hv = hr[kk];
    const float* wr = w + (size_t)kk*768;
    a0 += hv * wr[tid]; a1 += hv * wr[tid+256]; a2 += hv * wr[tid+512];
  }
  out[(size_t)b*768 + tid]       = tanhf(a0 + bias[tid]);
  out[(size_t)b*768 + tid + 256] = tanhf(a1 + bias[tid+256]);
  out[(size_t)b*768 + tid + 512] = tanhf(a2 + bias[tid+512]);
}

// ---------------------------------------------------------------- host
extern "C" void kernel_launch(void* const* d_in, const int* in_sizes, int n_in,
                              void* d_out, int out_size, void* d_ws, size_t ws_size,
                              hipStream_t stream) {
  const int*   ids   = (const int*)d_in[0];
  const int*   rel   = (const int*)d_in[1];
  const int*   amask = (const int*)d_in[2];
  const float* we    = (const float*)d_in[3];
  const float* pe    = (const float*)d_in[4];
  const float* te    = (const float*)d_in[5];
  const float* eg    = (const float*)d_in[6];
  const float* ebb   = (const float*)d_in[7];
  const float* Wq    = (const float*)d_in[8];
  const float* bq    = (const float*)d_in[9];
  const float* Wk    = (const float*)d_in[10];
  const float* bk    = (const float*)d_in[11];
  const float* Wv    = (const float*)d_in[12];
  const float* bv    = (const float*)d_in[13];
  const float* Wo    = (const float*)d_in[14];
  const float* bo    = (const float*)d_in[15];
  const float* g1    = (const float*)d_in[16];
  const float* b1    = (const float*)d_in[17];
  const float* Wi    = (const float*)d_in[18];
  const float* bi    = (const float*)d_in[19];
  const float* Wf    = (const float*)d_in[20];
  const float* bfp   = (const float*)d_in[21];
  const float* g2    = (const float*)d_in[22];
  const float* b2    = (const float*)d_in[23];
  const float* krel  = (const float*)d_in[24];
  const float* vrel  = (const float*)d_in[25];
  const float* pwp   = (const float*)d_in[26];
  const float* pbp   = (const float*)d_in[27];
  (void)in_sizes; (void)n_in; (void)out_size;

  char* ws = (char*)d_ws;
  size_t off = 0;
  auto take = [&](size_t bytes) { char* p = ws + off; off += (bytes + 255) & ~(size_t)255; return p; };
  u16*   hB   = (u16*)take((size_t)2048*768*2);
  u16*   atB  = (u16*)take((size_t)2048*768*2);
  u16*   qB   = (u16*)take((size_t)2048*768*2);
  u16*   kB   = (u16*)take((size_t)2048*768*2);
  u16*   vB   = (u16*)take((size_t)2048*768*2);
  u16*   ctxB = (u16*)take((size_t)2048*768*2);
  u16*   tmpB = (u16*)take((size_t)4*2048*768*2);     // 4 bf16 split-K partial planes
  u16*   ffB  = (u16*)take((size_t)2048*3072*2);
  float* wbF  = (float*)take((size_t)24576*50*4);
  const size_t PSTRIDE = (size_t)2048*768;

  // weight buffers: pre-convert all 12 layers in one launch if workspace allows
  const size_t WQKV = (size_t)2304*768, WWO = (size_t)768*768;
  const size_t WWI = (size_t)768*3072, WWF = (size_t)3072*768;
  const size_t wLayerBytes = (WQKV + WWO + WWI + WWF) * 2;
  const bool preall = (off + 12*wLayerBytes + 65536 <= ws_size);
  const int NL = preall ? 12 : 1;
  u16* wqkvB = (u16*)take(WQKV*2*NL);
  u16* woB   = (u16*)take(WWO*2*NL);
  u16* wiB   = (u16*)take(WWI*2*NL);
  u16* wfB   = (u16*)take(WWF*2*NL);

  ConvP cp{Wq, Wk, Wv, Wo, Wi, Wf, wqkvB, woB, wiB, wfB,
           preall ? (long)WQKV : 0, preall ? (long)WWO : 0,
           preall ? (long)WWI : 0, preall ? (long)WWF : 0};

  embed_ln<<<2048, 256, 0, stream>>>(ids, we, pe, te, eg, ebb, hB);
  if (preall) conv_weights<<<12*1728, 256, 0, stream>>>(cp, 0);

  for (int l = 0; l < 12; ++l) {
    if (!preall) conv_weights<<<1728, 256, 0, stream>>>(cp, l);
    const u16* wqkv_l = wqkvB + (size_t)l*cp.doqkv;
    const u16* wo_l   = woB   + (size_t)l*cp.doo;
    const u16* wi_l   = wiB   + (size_t)l*cp.doi;
    const u16* wf_l   = wfB   + (size_t)l*cp.dof;

    GP pq{}; pq.A = hB; pq.B = wqkv_l; pq.K = 768; pq.N = 2304;
    pq.bq = bq + l*768; pq.bk = bk + l*768; pq.bv = bv + l*768;
    pq.qO = qB; pq.kO = kB; pq.vO = vB;
    gemm_bt<64,128,4,0,1><<<dim3(18,32,1), 256, 0, stream>>>(pq);

    if (l == 6) {
      flash_attn<1><<<dim3(48,16), 256, 0, stream>>>(qB, kB, vB, amask, ctxB,
                                                     krel + 6*50*64, rel, wbF);
      rat_apply<<<768, 256, 0, stream>>>(wbF, vrel + 6*50*64, ctxB);
    } else {
      flash_attn<0><<<dim3(48,16), 256, 0, stream>>>(qB, kB, vB, amask, ctxB,
                                                     nullptr, nullptr, nullptr);
    }

    GP po{}; po.A = ctxB; po.B = wo_l; po.K = 768; po.N = 768; po.sOut = PSTRIDE;
    po.outB = tmpB;
    gemm_bt<64,128,4,2,2><<<dim3(6,32,2), 256, 0, stream>>>(po);
    ln_fused<<<2048, 256, 0, stream>>>(tmpB, tmpB + PSTRIDE, nullptr, nullptr, 2,
                                       bo + l*768, hB, g1 + l*768, b1 + l*768,
                                       nullptr, atB);

    GP pf1{}; pf1.A = atB; pf1.B = wi_l; pf1.K = 768; pf1.N = 3072;
    pf1.bias = bi + (size_t)l*3072; pf1.outB = ffB;
    gemm_bt<64,128,4,3,1><<<dim3(24,32,1), 256, 0, stream>>>(pf1);

    GP pf2{}; pf2.A = ffB; pf2.B = wf_l; pf2.K = 3072; pf2.N = 768; pf2.sOut = PSTRIDE;
    pf2.outB = tmpB;
    gemm_bt<64,128,4,2,4><<<dim3(6,32,4), 256, 0, stream>>>(pf2);
    // final layer: also write f32 h directly into d_out
    float* houtF = (l == 11) ? (float*)d_out : nullptr;
    ln_fused<<<2048, 256, 0, stream>>>(tmpB, tmpB + PSTRIDE, tmpB + 2*PSTRIDE, tmpB + 3*PSTRIDE, 4,
                                       bfp + l*768, atB, g2 + l*768, b2 + l*768,
                                       houtF, hB);
  }

  pooler_k<<<4, 256, 0, stream>>>((const float*)d_out, pwp, pbp, (float*)d_out + (size_t)2048*768);
}